// Round 1
// baseline (1016.031 us; speedup 1.0000x reference)
//
#include <hip/hip_runtime.h>

#define NN 10000
#define NE 160000
#define NE2 (NE + NN)
#define NG 64
#define NHEAD 4
#define EDIM 32

// ============================ preprocessing ============================

__global__ void k_deg_esum(const int* __restrict__ ei, const float* __restrict__ eattr,
                           int* __restrict__ deg, float* __restrict__ esum) {
    int e = blockIdx.x * blockDim.x + threadIdx.x;
    if (e >= NE) return;
    int dst = ei[NE + e];
    atomicAdd(&deg[dst], 1);
    const float* row = eattr + (size_t)e * EDIM;
    float* srow = esum + (size_t)dst * EDIM;
#pragma unroll
    for (int d = 0; d < EDIM; ++d) atomicAdd(&srow[d], row[d]);
}

// e2[e] = eattr[e] for e<NE ; e2[NE+n] = esum[n]/max(deg[n],1)
__global__ void k_build_e2(const float* __restrict__ eattr, const float* __restrict__ esum,
                           const int* __restrict__ deg, float* __restrict__ e2) {
    int i = blockIdx.x * blockDim.x + threadIdx.x;
    if (i >= NE2 * EDIM) return;
    int e = i / EDIM, d = i % EDIM;
    if (e < NE) {
        e2[i] = eattr[i];
    } else {
        int n = e - NE;
        e2[i] = esum[n * EDIM + d] / fmaxf((float)deg[n], 1.f);
    }
}

// row_ptr over (deg[n]+1) incoming edges per node; cursor = exclusive prefix copy
__global__ void k_scan(const int* __restrict__ deg, int* __restrict__ row_ptr,
                       int* __restrict__ cursor) {
    __shared__ int temp[1024];
    __shared__ int carry_s;
    if (threadIdx.x == 0) carry_s = 0;
    __syncthreads();
    for (int base = 0; base < NN; base += 1024) {
        int i = base + (int)threadIdx.x;
        int v = (i < NN) ? (deg[i] + 1) : 0;
        temp[threadIdx.x] = v;
        __syncthreads();
        for (int off = 1; off < 1024; off <<= 1) {
            int t = (threadIdx.x >= (unsigned)off) ? temp[threadIdx.x - off] : 0;
            __syncthreads();
            temp[threadIdx.x] += t;
            __syncthreads();
        }
        int incl = temp[threadIdx.x] + carry_s;
        if (i < NN) { row_ptr[i + 1] = incl; cursor[i] = incl - v; }
        __syncthreads();
        if (threadIdx.x == 1023) carry_s = incl;
        __syncthreads();
    }
    if (threadIdx.x == 0) row_ptr[0] = 0;
}

__global__ void k_fill(const int* __restrict__ ei, int* __restrict__ cursor,
                       int* __restrict__ src_sorted, int* __restrict__ eid_sorted) {
    int e = blockIdx.x * blockDim.x + threadIdx.x;
    if (e >= NE2) return;
    int src, dst;
    if (e < NE) { src = ei[e]; dst = ei[NE + e]; }
    else        { src = dst = e - NE; }
    int pos = atomicAdd(&cursor[dst], 1);
    src_sorted[pos] = src;
    eid_sorted[pos] = e;
}

// ============================ GEMM (fp32) ============================
// C[M,Nn] = A[M,K] @ B[K,Nn].  64x64 tile, 256 threads, 4x4 per thread.
#define BM 64
#define BN 64
#define BK 16

__global__ __launch_bounds__(256) void k_gemm(const float* __restrict__ A,
                                              const float* __restrict__ B,
                                              float* __restrict__ C,
                                              int M, int K, int Nn) {
    __shared__ float As[BK][BM + 1];
    __shared__ float Bs[BK][BN + 1];
    int bm = blockIdx.x * BM;
    int bn = blockIdx.y * BN;
    int tid = threadIdx.x;
    int tr = tid / 16, tc = tid % 16;
    float acc[4][4] = {};
    for (int k0 = 0; k0 < K; k0 += BK) {
        // A tile: thread i reads A[bm + i/BK][k0 + i%BK]
#pragma unroll
        for (int i = tid; i < BM * BK; i += 256) {
            int r = i / BK, kk = i % BK;
            int gr = bm + r;
            As[kk][r] = (gr < M) ? A[(size_t)gr * K + k0 + kk] : 0.f;
        }
        // B tile: thread i reads B[k0 + i/BN][bn + i%BN] (coalesced)
#pragma unroll
        for (int i = tid; i < BK * BN; i += 256) {
            int kk = i / BN, c = i % BN;
            Bs[kk][c] = B[(size_t)(k0 + kk) * Nn + bn + c];
        }
        __syncthreads();
#pragma unroll
        for (int kk = 0; kk < BK; ++kk) {
            float a[4], b[4];
#pragma unroll
            for (int i = 0; i < 4; ++i) a[i] = As[kk][tr * 4 + i];
#pragma unroll
            for (int j = 0; j < 4; ++j) b[j] = Bs[kk][tc * 4 + j];
#pragma unroll
            for (int i = 0; i < 4; ++i)
#pragma unroll
                for (int j = 0; j < 4; ++j) acc[i][j] += a[i] * b[j];
        }
        __syncthreads();
    }
#pragma unroll
    for (int i = 0; i < 4; ++i) {
        int gr = bm + tr * 4 + i;
        if (gr >= M) continue;
#pragma unroll
        for (int j = 0; j < 4; ++j)
            C[(size_t)gr * Nn + bn + tc * 4 + j] = acc[i][j];
    }
}

// ============================ per-layer kernels ============================

// Wf[d][h] = sum_c We[d, h*C+c] * ae[h, c]     (We: [EDIM, 4*C], ae: [4, C])
template <int C>
__global__ void k_fold(const float* __restrict__ We, const float* __restrict__ ae,
                       float* __restrict__ Wf) {
    int d = threadIdx.x / NHEAD, h = threadIdx.x % NHEAD; // 128 threads
    float s = 0.f;
    for (int c = 0; c < C; ++c) s += We[(size_t)d * (NHEAD * C) + h * C + c] * ae[h * C + c];
    Wf[d * NHEAD + h] = s;
}

// al_src[n,h] = <xs[n,h,:], as[h,:]> ; al_dst likewise. One wave per (node, head).
template <int C>
__global__ __launch_bounds__(256) void k_al_node(const float* __restrict__ xs,
                                                 const float* __restrict__ as_,
                                                 const float* __restrict__ ad_,
                                                 float* __restrict__ al_src,
                                                 float* __restrict__ al_dst) {
    int node = blockIdx.x;
    int h = threadIdx.x / 64, lane = threadIdx.x % 64;
    float s = 0.f, d = 0.f;
    const float* row = xs + (size_t)node * (NHEAD * C) + h * C;
#pragma unroll
    for (int c = lane; c < C; c += 64) {
        float v = row[c];
        s += v * as_[h * C + c];
        d += v * ad_[h * C + c];
    }
#pragma unroll
    for (int off = 32; off; off >>= 1) { s += __shfl_down(s, off); d += __shfl_down(d, off); }
    if (lane == 0) { al_src[node * NHEAD + h] = s; al_dst[node * NHEAD + h] = d; }
}

// al_edge[e,h] = e2[e,:] @ Wf[:,h]
__global__ __launch_bounds__(256) void k_al_edge(const float* __restrict__ e2,
                                                 const float* __restrict__ Wf,
                                                 float* __restrict__ al_edge) {
    __shared__ float wf[EDIM * NHEAD];
    if (threadIdx.x < EDIM * NHEAD) wf[threadIdx.x] = Wf[threadIdx.x];
    __syncthreads();
    int e = blockIdx.x * blockDim.x + threadIdx.x;
    if (e >= NE2) return;
    const float* row = e2 + (size_t)e * EDIM;
    float a0 = 0.f, a1 = 0.f, a2 = 0.f, a3 = 0.f;
#pragma unroll
    for (int d = 0; d < EDIM; ++d) {
        float v = row[d];
        a0 += v * wf[d * 4 + 0]; a1 += v * wf[d * 4 + 1];
        a2 += v * wf[d * 4 + 2]; a3 += v * wf[d * 4 + 3];
    }
    float* o = al_edge + (size_t)e * 4;
    o[0] = a0; o[1] = a1; o[2] = a2; o[3] = a3;
}

// segment softmax per (node, head); alpha buffer doubles as logit scratch.
__global__ __launch_bounds__(256) void k_softmax(const int* __restrict__ row_ptr,
                                                 const int* __restrict__ src_sorted,
                                                 const int* __restrict__ eid_sorted,
                                                 const float* __restrict__ al_src,
                                                 const float* __restrict__ al_dst,
                                                 const float* __restrict__ al_edge,
                                                 float* __restrict__ alpha) {
    int t = blockIdx.x * blockDim.x + threadIdx.x;
    if (t >= NN * NHEAD) return;
    int node = t / NHEAD, h = t % NHEAD;
    int beg = row_ptr[node], end = row_ptr[node + 1];
    float ad = al_dst[node * NHEAD + h];
    float m = -1e30f;
    for (int j = beg; j < end; ++j) {
        float lg = al_src[src_sorted[j] * NHEAD + h] + ad + al_edge[(size_t)eid_sorted[j] * NHEAD + h];
        lg = (lg >= 0.f) ? lg : 0.2f * lg;   // leaky_relu 0.2
        alpha[(size_t)j * NHEAD + h] = lg;
        m = fmaxf(m, lg);
    }
    float s = 0.f;
    for (int j = beg; j < end; ++j) {
        float ex = expf(alpha[(size_t)j * NHEAD + h] - m);
        alpha[(size_t)j * NHEAD + h] = ex;
        s += ex;
    }
    float inv = 1.f / (s + 1e-16f);
    for (int j = beg; j < end; ++j) alpha[(size_t)j * NHEAD + h] *= inv;
}

// out[n,c] = elu( mean_h sum_j alpha[j,h]*xs[src_j, h*C+c] + b[c] )
template <int HC, int C>
__global__ __launch_bounds__(256) void k_aggregate(const int* __restrict__ row_ptr,
                                                   const int* __restrict__ src_sorted,
                                                   const float* __restrict__ alpha,
                                                   const float* __restrict__ xs,
                                                   const float* __restrict__ bias,
                                                   float* __restrict__ hout) {
    constexpr int PER = HC / 256;
    int node = blockIdx.x;
    int tid = threadIdx.x;
    float acc[PER] = {};
    int beg = row_ptr[node], end = row_ptr[node + 1];
    for (int j = beg; j < end; ++j) {
        int s = src_sorted[j];
        const float* xrow = xs + (size_t)s * HC;
        const float* arow = alpha + (size_t)j * NHEAD;
#pragma unroll
        for (int p = 0; p < PER; ++p) {
            int idx = tid + p * 256;
            int h = idx / C;
            acc[p] += arow[h] * xrow[idx];
        }
    }
    __shared__ float red[HC];
#pragma unroll
    for (int p = 0; p < PER; ++p) red[tid + p * 256] = acc[p];
    __syncthreads();
    for (int c = tid; c < C; c += 256) {
        float v = 0.25f * (red[c] + red[C + c] + red[2 * C + c] + red[3 * C + c]) + bias[c];
        v = (v > 0.f) ? v : (expf(v) - 1.f);   // ELU
        hout[(size_t)node * C + c] = v;
    }
}

// ============================ pooling ============================

__global__ void k_pool(const float* __restrict__ h3, const int* __restrict__ batch,
                       float* __restrict__ outg, float* __restrict__ cntg) {
    int node = blockIdx.x;
    int c = threadIdx.x;  // 128
    int g = batch[node];
    atomicAdd(&outg[g * 128 + c], h3[(size_t)node * 128 + c]);
    if (c == 0) atomicAdd(&cntg[g], 1.f);
}

__global__ void k_pool_div(float* __restrict__ outg, const float* __restrict__ cntg) {
    int i = blockIdx.x * blockDim.x + threadIdx.x;
    if (i >= NG * 128) return;
    outg[i] /= fmaxf(cntg[i / 128], 1.f);
}

// ============================ host side ============================

struct Ws {
    float *e2, *xs, *hA, *hB, *al_src, *al_dst, *al_edge, *alpha, *esum, *Wf, *cntg;
    int *deg, *row_ptr, *cursor, *src_sorted, *eid_sorted;
};

static void carve(void* base, Ws& w) {
    char* p = (char*)base;
    size_t off = 0;
    auto take = [&](size_t bytes) {
        off = (off + 255) & ~(size_t)255;
        void* r = p + off;
        off += bytes;
        return r;
    };
    w.e2         = (float*)take((size_t)NE2 * EDIM * 4);
    w.xs         = (float*)take((size_t)NN * 1024 * 4);
    w.hA         = (float*)take((size_t)NN * 256 * 4);
    w.hB         = (float*)take((size_t)NN * 256 * 4);
    w.al_src     = (float*)take((size_t)NN * NHEAD * 4);
    w.al_dst     = (float*)take((size_t)NN * NHEAD * 4);
    w.al_edge    = (float*)take((size_t)NE2 * NHEAD * 4);
    w.alpha      = (float*)take((size_t)NE2 * NHEAD * 4);
    w.esum       = (float*)take((size_t)NN * EDIM * 4);
    w.Wf         = (float*)take(EDIM * NHEAD * 4);
    w.cntg       = (float*)take(NG * 4);
    w.deg        = (int*)take((size_t)NN * 4);
    w.row_ptr    = (int*)take((size_t)(NN + 1) * 4);
    w.cursor     = (int*)take((size_t)NN * 4);
    w.src_sorted = (int*)take((size_t)NE2 * 4);
    w.eid_sorted = (int*)take((size_t)NE2 * 4);
}

template <int CIN, int C>
static void run_layer(const float* hin, const float* Wl, const float* Wel,
                      const float* asl, const float* adl, const float* ael,
                      const float* bl, float* hout, Ws& w, hipStream_t stream) {
    constexpr int HC = NHEAD * C;
    dim3 gg((NN + BM - 1) / BM, HC / BN);
    k_gemm<<<gg, 256, 0, stream>>>(hin, Wl, w.xs, NN, CIN, HC);
    k_fold<C><<<1, 128, 0, stream>>>(Wel, ael, w.Wf);
    k_al_node<C><<<NN, 256, 0, stream>>>(w.xs, asl, adl, w.al_src, w.al_dst);
    k_al_edge<<<(NE2 + 255) / 256, 256, 0, stream>>>(w.e2, w.Wf, w.al_edge);
    k_softmax<<<(NN * NHEAD + 255) / 256, 256, 0, stream>>>(w.row_ptr, w.src_sorted,
                                                            w.eid_sorted, w.al_src,
                                                            w.al_dst, w.al_edge, w.alpha);
    k_aggregate<HC, C><<<NN, 256, 0, stream>>>(w.row_ptr, w.src_sorted, w.alpha, w.xs,
                                               bl, hout);
}

extern "C" void kernel_launch(void* const* d_in, const int* in_sizes, int n_in,
                              void* d_out, int out_size, void* d_ws, size_t ws_size,
                              hipStream_t stream) {
    const float* x     = (const float*)d_in[0];
    const int*   ei    = (const int*)d_in[1];
    const float* eattr = (const float*)d_in[2];
    const int*   batch = (const int*)d_in[3];
    const float* W[3]  = {(const float*)d_in[4],  (const float*)d_in[10], (const float*)d_in[16]};
    const float* We[3] = {(const float*)d_in[5],  (const float*)d_in[11], (const float*)d_in[17]};
    const float* as_[3]= {(const float*)d_in[6],  (const float*)d_in[12], (const float*)d_in[18]};
    const float* ad_[3]= {(const float*)d_in[7],  (const float*)d_in[13], (const float*)d_in[19]};
    const float* ae_[3]= {(const float*)d_in[8],  (const float*)d_in[14], (const float*)d_in[20]};
    const float* b_[3] = {(const float*)d_in[9],  (const float*)d_in[15], (const float*)d_in[21]};
    float* out = (float*)d_out;

    Ws w;
    carve(d_ws, w);

    hipMemsetAsync(w.deg,  0, (size_t)NN * 4, stream);
    hipMemsetAsync(w.esum, 0, (size_t)NN * EDIM * 4, stream);
    hipMemsetAsync(w.cntg, 0, NG * 4, stream);
    hipMemsetAsync(out,    0, (size_t)NG * 128 * 4, stream);

    // ---- graph preprocessing (CSR by dst + self-loop edge attrs) ----
    k_deg_esum<<<(NE + 255) / 256, 256, 0, stream>>>(ei, eattr, w.deg, w.esum);
    k_build_e2<<<((size_t)NE2 * EDIM + 255) / 256, 256, 0, stream>>>(eattr, w.esum, w.deg, w.e2);
    k_scan<<<1, 1024, 0, stream>>>(w.deg, w.row_ptr, w.cursor);
    k_fill<<<(NE2 + 255) / 256, 256, 0, stream>>>(ei, w.cursor, w.src_sorted, w.eid_sorted);

    // ---- 3 GAT layers ----
    run_layer<128, 128>(x,    W[0], We[0], as_[0], ad_[0], ae_[0], b_[0], w.hA, w, stream);
    run_layer<128, 256>(w.hA, W[1], We[1], as_[1], ad_[1], ae_[1], b_[1], w.hB, w, stream);
    run_layer<256, 128>(w.hB, W[2], We[2], as_[2], ad_[2], ae_[2], b_[2], w.hA, w, stream);

    // ---- global mean pool ----
    k_pool<<<NN, 128, 0, stream>>>(w.hA, batch, out, w.cntg);
    k_pool_div<<<(NG * 128 + 255) / 256, 256, 0, stream>>>(out, w.cntg);
}

// Round 2
// 645.044 us; speedup vs baseline: 1.5751x; 1.5751x over previous
//
#include <hip/hip_runtime.h>

#define NN 10000
#define NE 160000
#define NE2 (NE + NN)
#define NG 64
#define NHEAD 4
#define EDIM 32

__device__ __forceinline__ float lrelu(float x) { return x >= 0.f ? x : 0.2f * x; }
__device__ __forceinline__ float elu1(float x) { return x > 0.f ? x : expf(x) - 1.f; }

// ============================ preprocessing ============================

__global__ void k_deg(const int* __restrict__ ei, int* __restrict__ deg) {
    int e = blockIdx.x * blockDim.x + threadIdx.x;
    if (e >= NE) return;
    atomicAdd(&deg[ei[NE + e]], 1);
}

// row_ptr over (deg[n]+1) entries/node. 1 block, 1024 threads, 10 nodes/thread.
__global__ __launch_bounds__(1024) void k_scan2(const int* __restrict__ deg,
                                                int* __restrict__ row_ptr,
                                                int* __restrict__ cursor) {
    int tid = threadIdx.x;
    int vals[10];
    int run = 0;
#pragma unroll
    for (int i = 0; i < 10; ++i) {
        int n = tid * 10 + i;
        int v = (n < NN) ? (deg[n] + 1) : 0;
        run += v;
        vals[i] = run;  // inclusive within thread
    }
    int total = run;
    int lane = tid & 63, wid = tid >> 6;
    int sc = total;
#pragma unroll
    for (int off = 1; off < 64; off <<= 1) {
        int t = __shfl_up(sc, off);
        if (lane >= off) sc += t;
    }
    __shared__ int wsum[16];
    if (lane == 63) wsum[wid] = sc;
    __syncthreads();
    if (tid == 0) {
        int a = 0;
#pragma unroll
        for (int w = 0; w < 16; ++w) { int t = wsum[w]; wsum[w] = a; a += t; }
    }
    __syncthreads();
    int excl = sc - total + wsum[wid];
#pragma unroll
    for (int i = 0; i < 10; ++i) {
        int n = tid * 10 + i;
        if (n < NN) {
            int prev = i ? vals[i - 1] : 0;
            row_ptr[n + 1] = excl + vals[i];
            cursor[n] = excl + prev;
        }
    }
    if (tid == 0) row_ptr[0] = 0;
}

__global__ void k_fill(const int* __restrict__ ei, int* __restrict__ cursor,
                       int* __restrict__ src_sorted, int* __restrict__ eid_sorted,
                       int* __restrict__ pos) {
    int e = blockIdx.x * blockDim.x + threadIdx.x;
    if (e >= NE2) return;
    int s, d;
    if (e < NE) { s = ei[e]; d = ei[NE + e]; }
    else        { s = d = e - NE; }
    int p = atomicAdd(&cursor[d], 1);
    src_sorted[p] = s;
    eid_sorted[p] = e;
    pos[e] = p;
}

// esum[n,0:32] = sum of eattr over real incoming edges (CSR, no atomics)
__global__ __launch_bounds__(256) void k_esum(const int* __restrict__ row_ptr,
                                              const int* __restrict__ eid_sorted,
                                              const float* __restrict__ eattr,
                                              float* __restrict__ esum) {
    int wid = threadIdx.x >> 6, lane = threadIdx.x & 63;
    int node = blockIdx.x * 4 + wid;
    int d = lane & 31, sel = lane >> 5;
    int beg = row_ptr[node], end = row_ptr[node + 1];
    float v = 0.f;
    for (int j = beg + sel; j < end; j += 2) {
        int eid = eid_sorted[j];
        if (eid < NE) v += eattr[(size_t)eid * EDIM + d];
    }
    v += __shfl_xor(v, 32);
    if (sel == 0) esum[node * EDIM + d] = v;
}

// ============================ GEMM fp32 128x128x32, 8x8/thread ============================

#define BM2 128
#define BN2 128
#define BK2 32

__global__ __launch_bounds__(256) void k_gemm2(const float* __restrict__ A,
                                               const float* __restrict__ B,
                                               float* __restrict__ C,
                                               int M, int K, int Nn) {
    __shared__ float As[BK2][BM2 + 4];
    __shared__ float Bs[BK2][BN2 + 4];
    int bm = blockIdx.x * BM2, bn = blockIdx.y * BN2;
    int tid = threadIdx.x;
    int tr = tid / 16, tc = tid % 16;
    float acc[8][8] = {};
    for (int k0 = 0; k0 < K; k0 += BK2) {
        // A tile: 128 rows x 32 cols, transposed into As[kk][r]
#pragma unroll
        for (int it = 0; it < 4; ++it) {
            int r = tid / 8 + it * 32;
            int c4 = (tid % 8) * 4;
            int gr = bm + r;
            float4 av = make_float4(0.f, 0.f, 0.f, 0.f);
            if (gr < M) av = *(const float4*)(A + (size_t)gr * K + k0 + c4);
            As[c4 + 0][r] = av.x;
            As[c4 + 1][r] = av.y;
            As[c4 + 2][r] = av.z;
            As[c4 + 3][r] = av.w;
        }
        // B tile: 32 rows x 128 cols
#pragma unroll
        for (int it = 0; it < 4; ++it) {
            int rr = tid / 32 + it * 8;
            int cc = (tid % 32) * 4;
            float4 bv = *(const float4*)(B + (size_t)(k0 + rr) * Nn + bn + cc);
            *(float4*)&Bs[rr][cc] = bv;
        }
        __syncthreads();
#pragma unroll
        for (int kk = 0; kk < BK2; ++kk) {
            float4 a0 = *(const float4*)&As[kk][tr * 8];
            float4 a1 = *(const float4*)&As[kk][tr * 8 + 4];
            float4 b0 = *(const float4*)&Bs[kk][tc * 8];
            float4 b1 = *(const float4*)&Bs[kk][tc * 8 + 4];
            float a[8] = {a0.x, a0.y, a0.z, a0.w, a1.x, a1.y, a1.z, a1.w};
            float b[8] = {b0.x, b0.y, b0.z, b0.w, b1.x, b1.y, b1.z, b1.w};
#pragma unroll
            for (int i = 0; i < 8; ++i)
#pragma unroll
                for (int j = 0; j < 8; ++j) acc[i][j] += a[i] * b[j];
        }
        __syncthreads();
    }
#pragma unroll
    for (int i = 0; i < 8; ++i) {
        int gr = bm + tr * 8 + i;
        if (gr >= M) continue;
        float* cp = C + (size_t)gr * Nn + bn + tc * 8;
        *(float4*)cp = make_float4(acc[i][0], acc[i][1], acc[i][2], acc[i][3]);
        *(float4*)(cp + 4) = make_float4(acc[i][4], acc[i][5], acc[i][6], acc[i][7]);
    }
}

// ============================ per-layer kernels ============================

// Wf[d*4+h] = sum_c We[d, h*C+c] * ae[h, c]
template <int C>
__global__ void k_fold(const float* __restrict__ We, const float* __restrict__ ae,
                       float* __restrict__ Wf) {
    int t = threadIdx.x;  // 128 = EDIM*NHEAD
    int d = t >> 2, h = t & 3;
    const float* wr = We + (size_t)d * (NHEAD * C) + h * C;
    const float* ar = ae + h * C;
    float s = 0.f;
    for (int c = 0; c < C; ++c) s += wr[c] * ar[c];
    Wf[t] = s;
}

template <int C>
__global__ __launch_bounds__(256) void k_al_node(const float* __restrict__ xs,
                                                 const float* __restrict__ as_,
                                                 const float* __restrict__ ad_,
                                                 float* __restrict__ als,
                                                 float* __restrict__ ald) {
    int node = blockIdx.x;
    int h = threadIdx.x >> 6, lane = threadIdx.x & 63;
    const float* row = xs + (size_t)node * (NHEAD * C) + h * C;
    float s = 0.f, d = 0.f;
#pragma unroll
    for (int c = lane; c < C; c += 64) {
        float v = row[c];
        s += v * as_[h * C + c];
        d += v * ad_[h * C + c];
    }
#pragma unroll
    for (int off = 32; off; off >>= 1) { s += __shfl_down(s, off); d += __shfl_down(d, off); }
    if (lane == 0) { als[node * 4 + h] = s; ald[node * 4 + h] = d; }
}

// real-edge logits, written CSR-ordered
__global__ __launch_bounds__(256) void k_edge_logit(const int* __restrict__ ei,
                                                    const float* __restrict__ eattr,
                                                    const float* __restrict__ Wf,
                                                    const float* __restrict__ als,
                                                    const float* __restrict__ ald,
                                                    const int* __restrict__ pos,
                                                    float* __restrict__ lg) {
    __shared__ float wf[EDIM * NHEAD];
    if (threadIdx.x < EDIM * NHEAD) wf[threadIdx.x] = Wf[threadIdx.x];
    __syncthreads();
    int e = blockIdx.x * 256 + threadIdx.x;
    if (e >= NE) return;
    const float4* er = (const float4*)(eattr + (size_t)e * EDIM);
    float a0 = 0.f, a1 = 0.f, a2 = 0.f, a3 = 0.f;
#pragma unroll
    for (int d4 = 0; d4 < 8; ++d4) {
        float4 v = er[d4];
        const float* w = wf + d4 * 16;
        a0 += v.x * w[0] + v.y * w[4] + v.z * w[8] + v.w * w[12];
        a1 += v.x * w[1] + v.y * w[5] + v.z * w[9] + v.w * w[13];
        a2 += v.x * w[2] + v.y * w[6] + v.z * w[10] + v.w * w[14];
        a3 += v.x * w[3] + v.y * w[7] + v.z * w[11] + v.w * w[15];
    }
    int s = ei[e], d = ei[NE + e];
    float4 sv = ((const float4*)als)[s];
    float4 dv = ((const float4*)ald)[d];
    float4 r;
    r.x = lrelu(a0 + sv.x + dv.x);
    r.y = lrelu(a1 + sv.y + dv.y);
    r.z = lrelu(a2 + sv.z + dv.z);
    r.w = lrelu(a3 + sv.w + dv.w);
    ((float4*)lg)[pos[e]] = r;
}

// self-loop logits via linearity: (esum/deg)·Wf
__global__ __launch_bounds__(256) void k_loop_logit(const float* __restrict__ esum,
                                                    const int* __restrict__ deg,
                                                    const float* __restrict__ Wf,
                                                    const float* __restrict__ als,
                                                    const float* __restrict__ ald,
                                                    const int* __restrict__ pos,
                                                    float* __restrict__ lg) {
    __shared__ float wf[EDIM * NHEAD];
    if (threadIdx.x < EDIM * NHEAD) wf[threadIdx.x] = Wf[threadIdx.x];
    __syncthreads();
    int n = blockIdx.x * 256 + threadIdx.x;
    if (n >= NN) return;
    float inv = 1.f / fmaxf((float)deg[n], 1.f);
    const float4* er = (const float4*)(esum + (size_t)n * EDIM);
    float a0 = 0.f, a1 = 0.f, a2 = 0.f, a3 = 0.f;
#pragma unroll
    for (int d4 = 0; d4 < 8; ++d4) {
        float4 v = er[d4];
        const float* w = wf + d4 * 16;
        a0 += v.x * w[0] + v.y * w[4] + v.z * w[8] + v.w * w[12];
        a1 += v.x * w[1] + v.y * w[5] + v.z * w[9] + v.w * w[13];
        a2 += v.x * w[2] + v.y * w[6] + v.z * w[10] + v.w * w[14];
        a3 += v.x * w[3] + v.y * w[7] + v.z * w[11] + v.w * w[15];
    }
    float4 sv = ((const float4*)als)[n];
    float4 dv = ((const float4*)ald)[n];
    float4 r;
    r.x = lrelu(a0 * inv + sv.x + dv.x);
    r.y = lrelu(a1 * inv + sv.y + dv.y);
    r.z = lrelu(a2 * inv + sv.z + dv.z);
    r.w = lrelu(a3 * inv + sv.w + dv.w);
    ((float4*)lg)[pos[NE + n]] = r;
}

// fused softmax + weighted aggregate + head-mean + bias + ELU. One wave/node.
template <int C>
__global__ __launch_bounds__(256) void k_agg(const int* __restrict__ row_ptr,
                                             const int* __restrict__ src_sorted,
                                             const float* __restrict__ lg,
                                             const float* __restrict__ xs,
                                             const float* __restrict__ bias,
                                             float* __restrict__ hout) {
    constexpr int HC = 4 * C;
    constexpr int P4 = C / 64;  // float4 slots per lane
    int wid = threadIdx.x >> 6, lane = threadIdx.x & 63;
    int node = blockIdx.x * 4 + wid;
    int beg = row_ptr[node], end = row_ptr[node + 1];
    const float4* lg4 = (const float4*)lg;

    float4 m = make_float4(-1e30f, -1e30f, -1e30f, -1e30f);
    for (int j = beg; j < end; ++j) {
        float4 l = lg4[j];
        m.x = fmaxf(m.x, l.x); m.y = fmaxf(m.y, l.y);
        m.z = fmaxf(m.z, l.z); m.w = fmaxf(m.w, l.w);
    }

    float4 s = make_float4(0.f, 0.f, 0.f, 0.f);
    float4 acc[P4];
#pragma unroll
    for (int p = 0; p < P4; ++p) acc[p] = make_float4(0.f, 0.f, 0.f, 0.f);
    int half = lane >> 5;

    for (int j = beg; j < end; ++j) {
        float4 l = lg4[j];
        float4 ex;
        ex.x = expf(l.x - m.x); ex.y = expf(l.y - m.y);
        ex.z = expf(l.z - m.z); ex.w = expf(l.w - m.w);
        s.x += ex.x; s.y += ex.y; s.z += ex.z; s.w += ex.w;
        const float4* xr = (const float4*)(xs + (size_t)src_sorted[j] * HC);
#pragma unroll
        for (int p = 0; p < P4; ++p) {
            float w;
            if (C == 256) {
                w = (p == 0) ? ex.x : (p == 1) ? ex.y : (p == 2) ? ex.z : ex.w;
            } else {  // C==128: head = p*2 + half
                if (p == 0) w = half ? ex.y : ex.x;
                else        w = half ? ex.w : ex.z;
            }
            float4 v = xr[lane + p * 64];
            acc[p].x += w * v.x; acc[p].y += w * v.y;
            acc[p].z += w * v.z; acc[p].w += w * v.w;
        }
    }
    s.x += 1e-16f; s.y += 1e-16f; s.z += 1e-16f; s.w += 1e-16f;

    if (C == 256) {
        float4 r;
        r.x = acc[0].x / s.x + acc[1].x / s.y + acc[2].x / s.z + acc[3].x / s.w;
        r.y = acc[0].y / s.x + acc[1].y / s.y + acc[2].y / s.z + acc[3].y / s.w;
        r.z = acc[0].z / s.x + acc[1].z / s.y + acc[2].z / s.z + acc[3].z / s.w;
        r.w = acc[0].w / s.x + acc[1].w / s.y + acc[2].w / s.z + acc[3].w / s.w;
        float4 b = ((const float4*)bias)[lane];
        r.x = elu1(0.25f * r.x + b.x); r.y = elu1(0.25f * r.y + b.y);
        r.z = elu1(0.25f * r.z + b.z); r.w = elu1(0.25f * r.w + b.w);
        ((float4*)(hout + (size_t)node * C))[lane] = r;
    } else {
        float sA = half ? s.y : s.x;
        float sB = half ? s.w : s.z;
        float4 r;
        r.x = acc[0].x / sA + acc[1].x / sB;
        r.y = acc[0].y / sA + acc[1].y / sB;
        r.z = acc[0].z / sA + acc[1].z / sB;
        r.w = acc[0].w / sA + acc[1].w / sB;
        r.x += __shfl_xor(r.x, 32); r.y += __shfl_xor(r.y, 32);
        r.z += __shfl_xor(r.z, 32); r.w += __shfl_xor(r.w, 32);
        float4 b = ((const float4*)bias)[lane & 31];
        r.x = elu1(0.25f * r.x + b.x); r.y = elu1(0.25f * r.y + b.y);
        r.z = elu1(0.25f * r.z + b.z); r.w = elu1(0.25f * r.w + b.w);
        if (half == 0) ((float4*)(hout + (size_t)node * C))[lane] = r;
    }
}

// ============================ pooling (batch is sorted) ============================

__global__ void k_pool(const float* __restrict__ h, const int* __restrict__ batch,
                       float* __restrict__ out) {
    int g = blockIdx.x;   // 64
    int c = threadIdx.x;  // 128
    int lo = 0, hi = NN;
    while (lo < hi) { int mid = (lo + hi) >> 1; if (batch[mid] < g) lo = mid + 1; else hi = mid; }
    int start = lo;
    lo = start; hi = NN;
    while (lo < hi) { int mid = (lo + hi) >> 1; if (batch[mid] < g + 1) lo = mid + 1; else hi = mid; }
    int stop = lo;
    float v = 0.f;
    for (int n = start; n < stop; ++n) v += h[(size_t)n * 128 + c];
    out[g * 128 + c] = v / fmaxf((float)(stop - start), 1.f);
}

// ============================ host side ============================

struct Ws {
    float *xs, *hA, *hB, *als, *ald, *esum, *Wf, *lg;
    int *deg, *row_ptr, *cursor, *src_sorted, *eid_sorted, *pos;
};

static void carve(void* base, Ws& w) {
    char* p = (char*)base;
    size_t off = 0;
    auto take = [&](size_t bytes) {
        off = (off + 255) & ~(size_t)255;
        void* r = p + off;
        off += bytes;
        return r;
    };
    w.xs         = (float*)take((size_t)NN * 1024 * 4);
    w.hA         = (float*)take((size_t)NN * 128 * 4);
    w.hB         = (float*)take((size_t)NN * 256 * 4);
    w.als        = (float*)take((size_t)NN * 4 * 4);
    w.ald        = (float*)take((size_t)NN * 4 * 4);
    w.esum       = (float*)take((size_t)NN * EDIM * 4);
    w.Wf         = (float*)take(EDIM * NHEAD * 4);
    w.lg         = (float*)take((size_t)NE2 * 4 * 4);
    w.deg        = (int*)take((size_t)NN * 4);
    w.row_ptr    = (int*)take((size_t)(NN + 1) * 4);
    w.cursor     = (int*)take((size_t)NN * 4);
    w.src_sorted = (int*)take((size_t)NE2 * 4);
    w.eid_sorted = (int*)take((size_t)NE2 * 4);
    w.pos        = (int*)take((size_t)NE2 * 4);
}

template <int CIN, int C>
static void run_layer(const float* hin, const float* Wl, const float* Wel,
                      const float* asl, const float* adl, const float* ael,
                      const float* bl, const int* ei, const float* eattr,
                      float* hout, Ws& w, hipStream_t stream) {
    constexpr int HC = NHEAD * C;
    dim3 gg((NN + BM2 - 1) / BM2, HC / BN2);
    k_gemm2<<<gg, 256, 0, stream>>>(hin, Wl, w.xs, NN, CIN, HC);
    k_fold<C><<<1, 128, 0, stream>>>(Wel, ael, w.Wf);
    k_al_node<C><<<NN, 256, 0, stream>>>(w.xs, asl, adl, w.als, w.ald);
    k_edge_logit<<<(NE + 255) / 256, 256, 0, stream>>>(ei, eattr, w.Wf, w.als, w.ald,
                                                       w.pos, w.lg);
    k_loop_logit<<<(NN + 255) / 256, 256, 0, stream>>>(w.esum, w.deg, w.Wf, w.als, w.ald,
                                                       w.pos, w.lg);
    k_agg<C><<<NN / 4, 256, 0, stream>>>(w.row_ptr, w.src_sorted, w.lg, w.xs, bl, hout);
}

extern "C" void kernel_launch(void* const* d_in, const int* in_sizes, int n_in,
                              void* d_out, int out_size, void* d_ws, size_t ws_size,
                              hipStream_t stream) {
    const float* x     = (const float*)d_in[0];
    const int*   ei    = (const int*)d_in[1];
    const float* eattr = (const float*)d_in[2];
    const int*   batch = (const int*)d_in[3];
    const float* W[3]  = {(const float*)d_in[4],  (const float*)d_in[10], (const float*)d_in[16]};
    const float* We[3] = {(const float*)d_in[5],  (const float*)d_in[11], (const float*)d_in[17]};
    const float* as_[3]= {(const float*)d_in[6],  (const float*)d_in[12], (const float*)d_in[18]};
    const float* ad_[3]= {(const float*)d_in[7],  (const float*)d_in[13], (const float*)d_in[19]};
    const float* ae_[3]= {(const float*)d_in[8],  (const float*)d_in[14], (const float*)d_in[20]};
    const float* b_[3] = {(const float*)d_in[9],  (const float*)d_in[15], (const float*)d_in[21]};
    float* out = (float*)d_out;

    Ws w;
    carve(d_ws, w);

    hipMemsetAsync(w.deg, 0, (size_t)NN * 4, stream);

    // ---- preprocessing: CSR by dst, edge-attr sums (once) ----
    k_deg<<<(NE + 255) / 256, 256, 0, stream>>>(ei, w.deg);
    k_scan2<<<1, 1024, 0, stream>>>(w.deg, w.row_ptr, w.cursor);
    k_fill<<<(NE2 + 255) / 256, 256, 0, stream>>>(ei, w.cursor, w.src_sorted,
                                                  w.eid_sorted, w.pos);
    k_esum<<<NN / 4, 256, 0, stream>>>(w.row_ptr, w.eid_sorted, eattr, w.esum);

    // ---- 3 GAT layers ----
    run_layer<128, 128>(x,    W[0], We[0], as_[0], ad_[0], ae_[0], b_[0], ei, eattr, w.hA, w, stream);
    run_layer<128, 256>(w.hA, W[1], We[1], as_[1], ad_[1], ae_[1], b_[1], ei, eattr, w.hB, w, stream);
    run_layer<256, 128>(w.hB, W[2], We[2], as_[2], ad_[2], ae_[2], b_[2], ei, eattr, w.hA, w, stream);

    // ---- global mean pool ----
    k_pool<<<NG, 128, 0, stream>>>(w.hA, batch, out);
}

// Round 3
// 481.599 us; speedup vs baseline: 2.1097x; 1.3394x over previous
//
#include <hip/hip_runtime.h>

#define NN 10000
#define NE 160000
#define NE2 (NE + NN)
#define NG 64
#define NHEAD 4
#define EDIM 32

typedef _Float16 f16;
typedef __attribute__((ext_vector_type(8))) _Float16 f16x8;
typedef __attribute__((ext_vector_type(4))) float f32x4;
typedef __attribute__((ext_vector_type(8))) unsigned short u16x8;

__device__ __forceinline__ float lrelu(float x) { return x >= 0.f ? x : 0.2f * x; }
__device__ __forceinline__ float elu1(float x) { return x > 0.f ? x : expf(x) - 1.f; }

// ============================ preprocessing ============================

__global__ void k_deg(const int* __restrict__ ei, int* __restrict__ deg) {
    int e = blockIdx.x * blockDim.x + threadIdx.x;
    if (e >= NE) return;
    atomicAdd(&deg[ei[NE + e]], 1);
}

__global__ __launch_bounds__(1024) void k_scan2(const int* __restrict__ deg,
                                                int* __restrict__ row_ptr,
                                                int* __restrict__ cursor) {
    int tid = threadIdx.x;
    int vals[10];
    int run = 0;
#pragma unroll
    for (int i = 0; i < 10; ++i) {
        int n = tid * 10 + i;
        int v = (n < NN) ? (deg[n] + 1) : 0;
        run += v;
        vals[i] = run;
    }
    int total = run;
    int lane = tid & 63, wid = tid >> 6;
    int sc = total;
#pragma unroll
    for (int off = 1; off < 64; off <<= 1) {
        int t = __shfl_up(sc, off);
        if (lane >= off) sc += t;
    }
    __shared__ int wsum[16];
    if (lane == 63) wsum[wid] = sc;
    __syncthreads();
    if (tid == 0) {
        int a = 0;
#pragma unroll
        for (int w = 0; w < 16; ++w) { int t = wsum[w]; wsum[w] = a; a += t; }
    }
    __syncthreads();
    int excl = sc - total + wsum[wid];
#pragma unroll
    for (int i = 0; i < 10; ++i) {
        int n = tid * 10 + i;
        if (n < NN) {
            int prev = i ? vals[i - 1] : 0;
            row_ptr[n + 1] = excl + vals[i];
            cursor[n] = excl + prev;
        }
    }
    if (tid == 0) row_ptr[0] = 0;
}

__global__ void k_fill(const int* __restrict__ ei, int* __restrict__ cursor,
                       int* __restrict__ src_sorted, int* __restrict__ eid_sorted,
                       int* __restrict__ pos) {
    int e = blockIdx.x * blockDim.x + threadIdx.x;
    if (e >= NE2) return;
    int s, d;
    if (e < NE) { s = ei[e]; d = ei[NE + e]; }
    else        { s = d = e - NE; }
    int p = atomicAdd(&cursor[d], 1);
    src_sorted[p] = s;
    eid_sorted[p] = e;
    pos[e] = p;
}

__global__ __launch_bounds__(256) void k_esum(const int* __restrict__ row_ptr,
                                              const int* __restrict__ eid_sorted,
                                              const float* __restrict__ eattr,
                                              float* __restrict__ esum) {
    int wid = threadIdx.x >> 6, lane = threadIdx.x & 63;
    int node = blockIdx.x * 4 + wid;
    int d = lane & 31, sel = lane >> 5;
    int beg = row_ptr[node], end = row_ptr[node + 1];
    float v = 0.f;
    for (int j = beg + sel; j < end; j += 2) {
        int eid = eid_sorted[j];
        if (eid < NE) v += eattr[(size_t)eid * EDIM + d];
    }
    v += __shfl_xor(v, 32);
    if (sel == 0) esum[node * EDIM + d] = v;
}

// ============================ fp16 conversions ============================

__global__ void k_xcast(const float* __restrict__ x, f16* __restrict__ x16) {
    int i = blockIdx.x * blockDim.x + threadIdx.x;  // per 4 elems
    if (i * 4 >= NN * 128) return;
    float4 v = ((const float4*)x)[i];
    f16 o0 = (f16)v.x, o1 = (f16)v.y, o2 = (f16)v.z, o3 = (f16)v.w;
    f16* p = x16 + i * 4;
    p[0] = o0; p[1] = o1; p[2] = o2; p[3] = o3;
}

// W [K][NHC] fp32 -> Bt [NHC][K] fp16 (LDS tile transpose)
template <int K, int NHC>
__global__ __launch_bounds__(256) void k_wt(const float* __restrict__ W,
                                            f16* __restrict__ Bt) {
    __shared__ float t[32][33];
    int bi = blockIdx.x * 32, bo = blockIdx.y * 32;
    int tid = threadIdx.x;
#pragma unroll
    for (int it = 0; it < 4; ++it) {
        int i = tid / 32 + it * 8, o = tid % 32;
        t[i][o] = W[(size_t)(bi + i) * NHC + bo + o];
    }
    __syncthreads();
#pragma unroll
    for (int it = 0; it < 4; ++it) {
        int o = tid / 32 + it * 8, i = tid % 32;
        Bt[(size_t)(bo + o) * K + bi + i] = (f16)t[i][o];
    }
}

// ============================ MFMA fp16 GEMM ============================
// C[M,NHC] = A[M,K] @ Bt[NHC,K]^T. 128x128 tile, 4 waves of 64x64 each.
template <int K, int NHC>
__global__ __launch_bounds__(256) void k_gemm_h(const f16* __restrict__ A,
                                                const f16* __restrict__ Bt,
                                                f16* __restrict__ C) {
    __shared__ f16 Als[128 * 40];   // rows padded to 40 halfs (80B) -> conflict-free
    __shared__ f16 Bls[128 * 40];
    int bm = blockIdx.x * 128, bn = blockIdx.y * 128;
    int tid = threadIdx.x;
    int wid = tid >> 6, lane = tid & 63;
    int wr = (wid >> 1) * 64, wc = (wid & 1) * 64;
    int fr = lane & 15, fk = (lane >> 4) * 8;

    f32x4 acc[4][4];
#pragma unroll
    for (int m = 0; m < 4; ++m)
#pragma unroll
        for (int n = 0; n < 4; ++n) acc[m][n] = (f32x4){0.f, 0.f, 0.f, 0.f};

    for (int k0 = 0; k0 < K; k0 += 32) {
        // stage: 128 rows x 32 halfs each for A and B, 16B chunks
#pragma unroll
        for (int ch = tid; ch < 512; ch += 256) {
            int row = ch >> 2, part = ch & 3;
            int gr = bm + row;
            u16x8 va = (u16x8)0;
            if (gr < NN) va = *(const u16x8*)(A + (size_t)gr * K + k0 + part * 8);
            *(u16x8*)&Als[row * 40 + part * 8] = va;
            u16x8 vb = *(const u16x8*)(Bt + (size_t)(bn + row) * K + k0 + part * 8);
            *(u16x8*)&Bls[row * 40 + part * 8] = vb;
        }
        __syncthreads();
        f16x8 af[4], bf[4];
#pragma unroll
        for (int m = 0; m < 4; ++m)
            af[m] = *(const f16x8*)&Als[(wr + m * 16 + fr) * 40 + fk];
#pragma unroll
        for (int n = 0; n < 4; ++n)
            bf[n] = *(const f16x8*)&Bls[(wc + n * 16 + fr) * 40 + fk];
#pragma unroll
        for (int m = 0; m < 4; ++m)
#pragma unroll
            for (int n = 0; n < 4; ++n)
                acc[m][n] = __builtin_amdgcn_mfma_f32_16x16x32_f16(af[m], bf[n], acc[m][n], 0, 0, 0);
        __syncthreads();
    }

    int cr = (lane >> 4) * 4, cc = lane & 15;
#pragma unroll
    for (int m = 0; m < 4; ++m) {
#pragma unroll
        for (int r = 0; r < 4; ++r) {
            int row = bm + wr + m * 16 + cr + r;
            if (row >= NN) continue;
            f16* cp = C + (size_t)row * NHC + bn + wc + cc;
#pragma unroll
            for (int n = 0; n < 4; ++n) cp[n * 16] = (f16)acc[m][n][r];
        }
    }
}

// ============================ per-layer kernels ============================

template <int C>
__global__ void k_fold(const float* __restrict__ We, const float* __restrict__ ae,
                       float* __restrict__ Wf) {
    int t = threadIdx.x;  // 128
    int d = t >> 2, h = t & 3;
    const float* wr = We + (size_t)d * (NHEAD * C) + h * C;
    const float* ar = ae + h * C;
    float s = 0.f;
    for (int c = 0; c < C; ++c) s += wr[c] * ar[c];
    Wf[t] = s;
}

template <int C>
__global__ __launch_bounds__(256) void k_al_node(const f16* __restrict__ xs,
                                                 const float* __restrict__ as_,
                                                 const float* __restrict__ ad_,
                                                 float* __restrict__ als,
                                                 float* __restrict__ ald) {
    int node = blockIdx.x;
    int h = threadIdx.x >> 6, lane = threadIdx.x & 63;
    const f16* row = xs + (size_t)node * (NHEAD * C) + h * C;
    float s = 0.f, d = 0.f;
#pragma unroll
    for (int c = 2 * lane; c < C; c += 128) {
        float v0 = (float)row[c], v1 = (float)row[c + 1];
        s += v0 * as_[h * C + c] + v1 * as_[h * C + c + 1];
        d += v0 * ad_[h * C + c] + v1 * ad_[h * C + c + 1];
    }
#pragma unroll
    for (int off = 32; off; off >>= 1) { s += __shfl_down(s, off); d += __shfl_down(d, off); }
    if (lane == 0) { als[node * 4 + h] = s; ald[node * 4 + h] = d; }
}

__global__ __launch_bounds__(256) void k_edge_logit(const int* __restrict__ ei,
                                                    const float* __restrict__ eattr,
                                                    const float* __restrict__ Wf,
                                                    const float* __restrict__ als,
                                                    const float* __restrict__ ald,
                                                    const int* __restrict__ pos,
                                                    float* __restrict__ lg) {
    __shared__ float wf[EDIM * NHEAD];
    if (threadIdx.x < EDIM * NHEAD) wf[threadIdx.x] = Wf[threadIdx.x];
    __syncthreads();
    int e = blockIdx.x * 256 + threadIdx.x;
    if (e >= NE) return;
    const float4* er = (const float4*)(eattr + (size_t)e * EDIM);
    float a0 = 0.f, a1 = 0.f, a2 = 0.f, a3 = 0.f;
#pragma unroll
    for (int d4 = 0; d4 < 8; ++d4) {
        float4 v = er[d4];
        const float* w = wf + d4 * 16;
        a0 += v.x * w[0] + v.y * w[4] + v.z * w[8] + v.w * w[12];
        a1 += v.x * w[1] + v.y * w[5] + v.z * w[9] + v.w * w[13];
        a2 += v.x * w[2] + v.y * w[6] + v.z * w[10] + v.w * w[14];
        a3 += v.x * w[3] + v.y * w[7] + v.z * w[11] + v.w * w[15];
    }
    int s = ei[e], d = ei[NE + e];
    float4 sv = ((const float4*)als)[s];
    float4 dv = ((const float4*)ald)[d];
    float4 r;
    r.x = lrelu(a0 + sv.x + dv.x);
    r.y = lrelu(a1 + sv.y + dv.y);
    r.z = lrelu(a2 + sv.z + dv.z);
    r.w = lrelu(a3 + sv.w + dv.w);
    ((float4*)lg)[pos[e]] = r;
}

__global__ __launch_bounds__(256) void k_loop_logit(const float* __restrict__ esum,
                                                    const int* __restrict__ deg,
                                                    const float* __restrict__ Wf,
                                                    const float* __restrict__ als,
                                                    const float* __restrict__ ald,
                                                    const int* __restrict__ pos,
                                                    float* __restrict__ lg) {
    __shared__ float wf[EDIM * NHEAD];
    if (threadIdx.x < EDIM * NHEAD) wf[threadIdx.x] = Wf[threadIdx.x];
    __syncthreads();
    int n = blockIdx.x * 256 + threadIdx.x;
    if (n >= NN) return;
    float inv = 1.f / fmaxf((float)deg[n], 1.f);
    const float4* er = (const float4*)(esum + (size_t)n * EDIM);
    float a0 = 0.f, a1 = 0.f, a2 = 0.f, a3 = 0.f;
#pragma unroll
    for (int d4 = 0; d4 < 8; ++d4) {
        float4 v = er[d4];
        const float* w = wf + d4 * 16;
        a0 += v.x * w[0] + v.y * w[4] + v.z * w[8] + v.w * w[12];
        a1 += v.x * w[1] + v.y * w[5] + v.z * w[9] + v.w * w[13];
        a2 += v.x * w[2] + v.y * w[6] + v.z * w[10] + v.w * w[14];
        a3 += v.x * w[3] + v.y * w[7] + v.z * w[11] + v.w * w[15];
    }
    float4 sv = ((const float4*)als)[n];
    float4 dv = ((const float4*)ald)[n];
    float4 r;
    r.x = lrelu(a0 * inv + sv.x + dv.x);
    r.y = lrelu(a1 * inv + sv.y + dv.y);
    r.z = lrelu(a2 * inv + sv.z + dv.z);
    r.w = lrelu(a3 * inv + sv.w + dv.w);
    ((float4*)lg)[pos[NE + n]] = r;
}

// fused softmax + fp16 gather aggregate + head-mean + bias + ELU. One wave/node.
template <int C>
__global__ __launch_bounds__(256) void k_agg(const int* __restrict__ row_ptr,
                                             const int* __restrict__ src_sorted,
                                             const float* __restrict__ lg,
                                             const f16* __restrict__ xs,
                                             const float* __restrict__ bias,
                                             f16* __restrict__ hout) {
    constexpr int HC = 4 * C;
    constexpr int P = HC / 512;  // 16B chunks per lane: C=128 -> 1, C=256 -> 2
    int wid = threadIdx.x >> 6, lane = threadIdx.x & 63;
    int node = blockIdx.x * 4 + wid;
    int beg = row_ptr[node], end = row_ptr[node + 1];
    const float4* lg4 = (const float4*)lg;

    float4 m4 = make_float4(-1e30f, -1e30f, -1e30f, -1e30f);
    for (int j = beg; j < end; ++j) {
        float4 l = lg4[j];
        m4.x = fmaxf(m4.x, l.x); m4.y = fmaxf(m4.y, l.y);
        m4.z = fmaxf(m4.z, l.z); m4.w = fmaxf(m4.w, l.w);
    }

    float s[4] = {0.f, 0.f, 0.f, 0.f};
    float acc[P][8];
#pragma unroll
    for (int p = 0; p < P; ++p)
#pragma unroll
        for (int i = 0; i < 8; ++i) acc[p][i] = 0.f;

    for (int j = beg; j < end; ++j) {
        float4 l = lg4[j];
        float ex[4];
        ex[0] = expf(l.x - m4.x); ex[1] = expf(l.y - m4.y);
        ex[2] = expf(l.z - m4.z); ex[3] = expf(l.w - m4.w);
        s[0] += ex[0]; s[1] += ex[1]; s[2] += ex[2]; s[3] += ex[3];
        const f16x8* xr = (const f16x8*)(xs + (size_t)src_sorted[j] * HC);
#pragma unroll
        for (int p = 0; p < P; ++p) {
            float w = (C == 128) ? ex[lane >> 4] : ex[(lane >> 5) + 2 * p];
            f16x8 v = xr[lane + p * 64];
#pragma unroll
            for (int i = 0; i < 8; ++i) acc[p][i] += w * (float)v[i];
        }
    }

    if (C == 128) {
        float inv = 1.f / (s[lane >> 4] + 1e-16f);
        float r[8];
#pragma unroll
        for (int i = 0; i < 8; ++i) {
            r[i] = acc[0][i] * inv;
            r[i] += __shfl_xor(r[i], 16);
            r[i] += __shfl_xor(r[i], 32);
        }
        if (lane < 16) {
            f16x8 o;
#pragma unroll
            for (int i = 0; i < 8; ++i)
                o[i] = (f16)elu1(0.25f * r[i] + bias[lane * 8 + i]);
            *(f16x8*)(hout + (size_t)node * C + lane * 8) = o;
        }
    } else {
        float i0 = 1.f / (s[(lane >> 5)] + 1e-16f);
        float i1 = 1.f / (s[(lane >> 5) + 2] + 1e-16f);
        float r[8];
#pragma unroll
        for (int i = 0; i < 8; ++i) {
            r[i] = acc[0][i] * i0 + acc[1][i] * i1;
            r[i] += __shfl_xor(r[i], 32);
        }
        if (lane < 32) {
            f16x8 o;
#pragma unroll
            for (int i = 0; i < 8; ++i)
                o[i] = (f16)elu1(0.25f * r[i] + bias[lane * 8 + i]);
            *(f16x8*)(hout + (size_t)node * C + lane * 8) = o;
        }
    }
}

// ============================ pooling (batch sorted) ============================

__global__ void k_pool(const f16* __restrict__ h, const int* __restrict__ batch,
                       float* __restrict__ out) {
    int g = blockIdx.x;   // 64
    int c = threadIdx.x;  // 128
    int lo = 0, hi = NN;
    while (lo < hi) { int mid = (lo + hi) >> 1; if (batch[mid] < g) lo = mid + 1; else hi = mid; }
    int start = lo;
    lo = start; hi = NN;
    while (lo < hi) { int mid = (lo + hi) >> 1; if (batch[mid] < g + 1) lo = mid + 1; else hi = mid; }
    int stop = lo;
    float v = 0.f;
    for (int n = start; n < stop; ++n) v += (float)h[(size_t)n * 128 + c];
    out[g * 128 + c] = v / fmaxf((float)(stop - start), 1.f);
}

// ============================ host side ============================

struct Ws {
    f16 *x16, *xs, *hA, *hB, *Wt;
    float *als, *ald, *esum, *Wf, *lg;
    int *deg, *row_ptr, *cursor, *src_sorted, *eid_sorted, *pos;
};

static void carve(void* base, Ws& w) {
    char* p = (char*)base;
    size_t off = 0;
    auto take = [&](size_t bytes) {
        off = (off + 255) & ~(size_t)255;
        void* r = p + off;
        off += bytes;
        return r;
    };
    w.x16        = (f16*)take((size_t)NN * 128 * 2);
    w.xs         = (f16*)take((size_t)NN * 1024 * 2);
    w.hA         = (f16*)take((size_t)NN * 128 * 2);
    w.hB         = (f16*)take((size_t)NN * 256 * 2);
    w.Wt         = (f16*)take((size_t)1024 * 256 * 2);
    w.als        = (float*)take((size_t)NN * 4 * 4);
    w.ald        = (float*)take((size_t)NN * 4 * 4);
    w.esum       = (float*)take((size_t)NN * EDIM * 4);
    w.Wf         = (float*)take(EDIM * NHEAD * 4);
    w.lg         = (float*)take((size_t)NE2 * 4 * 4);
    w.deg        = (int*)take((size_t)NN * 4);
    w.row_ptr    = (int*)take((size_t)(NN + 1) * 4);
    w.cursor     = (int*)take((size_t)NN * 4);
    w.src_sorted = (int*)take((size_t)NE2 * 4);
    w.eid_sorted = (int*)take((size_t)NE2 * 4);
    w.pos        = (int*)take((size_t)NE2 * 4);
}

template <int CIN, int C>
static void run_layer(const f16* hin, const float* Wl, const float* Wel,
                      const float* asl, const float* adl, const float* ael,
                      const float* bl, const int* ei, const float* eattr,
                      f16* hout, Ws& w, hipStream_t stream) {
    constexpr int HC = NHEAD * C;
    k_wt<CIN, HC><<<dim3(CIN / 32, HC / 32), 256, 0, stream>>>(Wl, w.Wt);
    k_gemm_h<CIN, HC><<<dim3((NN + 127) / 128, HC / 128), 256, 0, stream>>>(hin, w.Wt, w.xs);
    k_fold<C><<<1, 128, 0, stream>>>(Wel, ael, w.Wf);
    k_al_node<C><<<NN, 256, 0, stream>>>(w.xs, asl, adl, w.als, w.ald);
    k_edge_logit<<<(NE + 255) / 256, 256, 0, stream>>>(ei, eattr, w.Wf, w.als, w.ald,
                                                       w.pos, w.lg);
    k_loop_logit<<<(NN + 255) / 256, 256, 0, stream>>>(w.esum, w.deg, w.Wf, w.als, w.ald,
                                                       w.pos, w.lg);
    k_agg<C><<<NN / 4, 256, 0, stream>>>(w.row_ptr, w.src_sorted, w.lg, w.xs, bl, hout);
}

extern "C" void kernel_launch(void* const* d_in, const int* in_sizes, int n_in,
                              void* d_out, int out_size, void* d_ws, size_t ws_size,
                              hipStream_t stream) {
    const float* x     = (const float*)d_in[0];
    const int*   ei    = (const int*)d_in[1];
    const float* eattr = (const float*)d_in[2];
    const int*   batch = (const int*)d_in[3];
    const float* W[3]  = {(const float*)d_in[4],  (const float*)d_in[10], (const float*)d_in[16]};
    const float* We[3] = {(const float*)d_in[5],  (const float*)d_in[11], (const float*)d_in[17]};
    const float* as_[3]= {(const float*)d_in[6],  (const float*)d_in[12], (const float*)d_in[18]};
    const float* ad_[3]= {(const float*)d_in[7],  (const float*)d_in[13], (const float*)d_in[19]};
    const float* ae_[3]= {(const float*)d_in[8],  (const float*)d_in[14], (const float*)d_in[20]};
    const float* b_[3] = {(const float*)d_in[9],  (const float*)d_in[15], (const float*)d_in[21]};
    float* out = (float*)d_out;

    Ws w;
    carve(d_ws, w);

    hipMemsetAsync(w.deg, 0, (size_t)NN * 4, stream);

    // ---- preprocessing: CSR by dst, edge-attr sums, fp16 input cast ----
    k_deg<<<(NE + 255) / 256, 256, 0, stream>>>(ei, w.deg);
    k_scan2<<<1, 1024, 0, stream>>>(w.deg, w.row_ptr, w.cursor);
    k_fill<<<(NE2 + 255) / 256, 256, 0, stream>>>(ei, w.cursor, w.src_sorted,
                                                  w.eid_sorted, w.pos);
    k_esum<<<NN / 4, 256, 0, stream>>>(w.row_ptr, w.eid_sorted, eattr, w.esum);
    k_xcast<<<(NN * 128 / 4 + 255) / 256, 256, 0, stream>>>(x, w.x16);

    // ---- 3 GAT layers ----
    run_layer<128, 128>(w.x16, W[0], We[0], as_[0], ad_[0], ae_[0], b_[0], ei, eattr, w.hA, w, stream);
    run_layer<128, 256>(w.hA,  W[1], We[1], as_[1], ad_[1], ae_[1], b_[1], ei, eattr, w.hB, w, stream);
    run_layer<256, 128>(w.hB,  W[2], We[2], as_[2], ad_[2], ae_[2], b_[2], ei, eattr, w.hA, w, stream);

    // ---- global mean pool ----
    k_pool<<<NG, 128, 0, stream>>>(w.hA, batch, out);
}

// Round 4
// 396.119 us; speedup vs baseline: 2.5650x; 1.2158x over previous
//
#include <hip/hip_runtime.h>

#define NN 10000
#define NE 160000
#define NE2 (NE + NN)
#define NG 64
#define EDIM 32

typedef _Float16 f16;
typedef __attribute__((ext_vector_type(2))) _Float16 f16x2;
typedef __attribute__((ext_vector_type(4))) _Float16 f16x4;
typedef __attribute__((ext_vector_type(8))) _Float16 f16x8;
typedef __attribute__((ext_vector_type(4))) float f32x4;
typedef __attribute__((ext_vector_type(8))) unsigned short u16x8;

__device__ __forceinline__ float lrelu(float x) { return fmaxf(x, 0.2f * x); }
__device__ __forceinline__ float elu1(float x) { return x > 0.f ? x : __expf(x) - 1.f; }

// ============================ preprocessing ============================

__global__ void k_deg(const int* __restrict__ ei, int* __restrict__ deg) {
    int e = blockIdx.x * blockDim.x + threadIdx.x;
    if (e >= NE) return;
    atomicAdd(&deg[ei[NE + e]], 1);
}

__global__ __launch_bounds__(1024) void k_scan2(const int* __restrict__ deg,
                                                int* __restrict__ row_ptr,
                                                int* __restrict__ cursor) {
    int tid = threadIdx.x;
    int vals[10];
    int run = 0;
#pragma unroll
    for (int i = 0; i < 10; ++i) {
        int n = tid * 10 + i;
        int v = (n < NN) ? (deg[n] + 1) : 0;
        run += v;
        vals[i] = run;
    }
    int total = run;
    int lane = tid & 63, wid = tid >> 6;
    int sc = total;
#pragma unroll
    for (int off = 1; off < 64; off <<= 1) {
        int t = __shfl_up(sc, off);
        if (lane >= off) sc += t;
    }
    __shared__ int wsum[16];
    if (lane == 63) wsum[wid] = sc;
    __syncthreads();
    if (tid == 0) {
        int a = 0;
#pragma unroll
        for (int w = 0; w < 16; ++w) { int t = wsum[w]; wsum[w] = a; a += t; }
    }
    __syncthreads();
    int excl = sc - total + wsum[wid];
#pragma unroll
    for (int i = 0; i < 10; ++i) {
        int n = tid * 10 + i;
        if (n < NN) {
            int prev = i ? vals[i - 1] : 0;
            row_ptr[n + 1] = excl + vals[i];
            cursor[n] = excl + prev;
        }
    }
    if (tid == 0) row_ptr[0] = 0;
}

__global__ void k_fill(const int* __restrict__ ei, int* __restrict__ cursor,
                       int* __restrict__ src_sorted, int* __restrict__ eid_sorted,
                       int* __restrict__ pos) {
    int e = blockIdx.x * blockDim.x + threadIdx.x;
    if (e >= NE2) return;
    int s, d;
    if (e < NE) { s = ei[e]; d = ei[NE + e]; }
    else        { s = d = e - NE; }
    int p = atomicAdd(&cursor[d], 1);
    src_sorted[p] = s;
    eid_sorted[p] = e;
    pos[e] = p;
}

__global__ __launch_bounds__(256) void k_esum(const int* __restrict__ row_ptr,
                                              const int* __restrict__ eid_sorted,
                                              const float* __restrict__ eattr,
                                              float* __restrict__ esum) {
    int wid = threadIdx.x >> 6, lane = threadIdx.x & 63;
    int node = blockIdx.x * 4 + wid;
    int d = lane & 31, sel = lane >> 5;
    int beg = row_ptr[node], end = row_ptr[node + 1];
    float v = 0.f;
    for (int j = beg + sel; j < end; j += 2) {
        int eid = eid_sorted[j];
        if (eid < NE) v += eattr[(size_t)eid * EDIM + d];
    }
    v += __shfl_xor(v, 32);
    if (sel == 0) esum[node * EDIM + d] = v;
}

__global__ void k_xcast(const float* __restrict__ x, f16* __restrict__ x16) {
    int i = blockIdx.x * blockDim.x + threadIdx.x;  // per 4 elems
    if (i * 4 >= NN * 128) return;
    float4 v = ((const float4*)x)[i];
    f16x4 o;
    o[0] = (f16)v.x; o[1] = (f16)v.y; o[2] = (f16)v.z; o[3] = (f16)v.w;
    *(f16x4*)(x16 + i * 4) = o;
}

// ========== weight prep per layer: Wstack^T (fp16) + folded âs/âd + Wf ==========
// Bt[c][h*CIN+k] = W[k][h*C+c]; asd = [âs|âd], âs[h][k] = Σ_c W[k,hC+c]·as[h,c];
// Wf[d*4+h] = Σ_c We[d,hC+c]·ae[h,c]
template <int CIN, int C>
__global__ __launch_bounds__(256) void k_wprep(const float* __restrict__ W,
                                               const float* __restrict__ We,
                                               const float* __restrict__ as_,
                                               const float* __restrict__ ad_,
                                               const float* __restrict__ ae_,
                                               f16* __restrict__ Bt,
                                               float* __restrict__ asd,
                                               float* __restrict__ Wf) {
    constexpr int K4 = 4 * CIN;
    constexpr int KT = CIN / 32, CT = C / 32;
    constexpr int TB = 4 * KT * CT;
    constexpr int FB = CIN / 64;
    int b = blockIdx.x;
    int tid = threadIdx.x;
    if (b < TB) {
        int h = b / (KT * CT);
        int rem = b % (KT * CT);
        int k0 = (rem / CT) * 32, c0 = (rem % CT) * 32;
        __shared__ float t[32][33];
        int i = tid >> 5, j = tid & 31;
#pragma unroll
        for (int it = 0; it < 4; ++it)
            t[i + it * 8][j] = W[(size_t)(k0 + i + it * 8) * (4 * C) + h * C + c0 + j];
        __syncthreads();
#pragma unroll
        for (int it = 0; it < 4; ++it) {
            int jj = (tid >> 5) + it * 8, ii = tid & 31;
            Bt[(size_t)(c0 + jj) * K4 + h * CIN + k0 + ii] = (f16)t[ii][jj];
        }
    } else if (b < TB + FB) {
        int k = (b - TB) * 64 + (tid >> 2), h = tid & 3;
        const float4* wr = (const float4*)(W + (size_t)k * (4 * C) + h * C);
        const float4* a4 = (const float4*)(as_ + h * C);
        const float4* d4 = (const float4*)(ad_ + h * C);
        float s = 0.f, d = 0.f;
        for (int c = 0; c < C / 4; ++c) {
            float4 w = wr[c], av = a4[c], dv = d4[c];
            s += w.x * av.x + w.y * av.y + w.z * av.z + w.w * av.w;
            d += w.x * dv.x + w.y * dv.y + w.z * dv.z + w.w * dv.w;
        }
        asd[h * CIN + k] = s;
        asd[4 * CIN + h * CIN + k] = d;
    } else if (tid < 128) {
        int dd = tid >> 2, h = tid & 3;
        const float4* wr = (const float4*)(We + (size_t)dd * (4 * C) + h * C);
        const float4* a4 = (const float4*)(ae_ + h * C);
        float s = 0.f;
        for (int c = 0; c < C / 4; ++c) {
            float4 w = wr[c], av = a4[c];
            s += w.x * av.x + w.y * av.y + w.z * av.z + w.w * av.w;
        }
        Wf[dd * 4 + h] = s;
    }
}

// per-edge attention contributions for all 3 layers, written CSR-ordered
__global__ __launch_bounds__(256) void k_e4(const float* __restrict__ eattr,
                                            const float* __restrict__ esum,
                                            const int* __restrict__ deg,
                                            const float* __restrict__ Wf1,
                                            const float* __restrict__ Wf2,
                                            const float* __restrict__ Wf3,
                                            const int* __restrict__ pos,
                                            float* __restrict__ e4all) {
    __shared__ float wf[3][128];
    int tid = threadIdx.x;
    if (tid < 128) { wf[0][tid] = Wf1[tid]; wf[1][tid] = Wf2[tid]; wf[2][tid] = Wf3[tid]; }
    __syncthreads();
    int e = blockIdx.x * 256 + tid;
    if (e >= NE2) return;
    const float4* er;
    float scale = 1.f;
    if (e < NE) {
        er = (const float4*)(eattr + (size_t)e * EDIM);
    } else {
        int n = e - NE;
        er = (const float4*)(esum + (size_t)n * EDIM);
        scale = 1.f / fmaxf((float)deg[n], 1.f);
    }
    float4 v[8];
#pragma unroll
    for (int i = 0; i < 8; ++i) v[i] = er[i];
    int p = pos[e];
#pragma unroll
    for (int l = 0; l < 3; ++l) {
        float a0 = 0.f, a1 = 0.f, a2 = 0.f, a3 = 0.f;
#pragma unroll
        for (int d4 = 0; d4 < 8; ++d4) {
            const float* w = &wf[l][d4 * 16];
            a0 += v[d4].x * w[0] + v[d4].y * w[4] + v[d4].z * w[8]  + v[d4].w * w[12];
            a1 += v[d4].x * w[1] + v[d4].y * w[5] + v[d4].z * w[9]  + v[d4].w * w[13];
            a2 += v[d4].x * w[2] + v[d4].y * w[6] + v[d4].z * w[10] + v[d4].w * w[14];
            a3 += v[d4].x * w[3] + v[d4].y * w[7] + v[d4].z * w[11] + v[d4].w * w[15];
        }
        ((float4*)e4all)[(size_t)l * NE2 + p] =
            make_float4(a0 * scale, a1 * scale, a2 * scale, a3 * scale);
    }
}

// als[n,h] = x'[n]·âs[h], ald likewise. Wave per node; lane = (h, 16-chunk).
template <int CIN>
__global__ __launch_bounds__(256) void k_alnode2(const f16* __restrict__ xp,
                                                 const float* __restrict__ asd,
                                                 float* __restrict__ als,
                                                 float* __restrict__ ald) {
    __shared__ float sA[4 * CIN], sD[4 * CIN];
    for (int i = threadIdx.x; i < 4 * CIN; i += 256) { sA[i] = asd[i]; sD[i] = asd[4 * CIN + i]; }
    __syncthreads();
    int wid = threadIdx.x >> 6, lane = threadIdx.x & 63;
    int node = blockIdx.x * 4 + wid;
    int h = lane >> 4, c16 = lane & 15;
    constexpr int KC = CIN / 16;
    const f16* xr = xp + (size_t)node * CIN + c16 * KC;
    float s = 0.f, d = 0.f;
#pragma unroll
    for (int p = 0; p < KC / 8; ++p) {
        f16x8 v = *(const f16x8*)(xr + p * 8);
        const float* wa = &sA[h * CIN + c16 * KC + p * 8];
        const float* wd = &sD[h * CIN + c16 * KC + p * 8];
#pragma unroll
        for (int i = 0; i < 8; ++i) {
            float f = (float)v[i];
            s += f * wa[i];
            d += f * wd[i];
        }
    }
#pragma unroll
    for (int off = 1; off < 16; off <<= 1) { s += __shfl_xor(s, off); d += __shfl_xor(d, off); }
    if (c16 == 0) { als[node * 4 + h] = s; ald[node * 4 + h] = d; }
}

// fused logits + softmax (no max pass) + INPUT-feature aggregation.
// aggcat[n, h*CIN+k] = Σ_j softmax_h(j)·x'[src_j, k].  Wave per node.
template <int CIN>
__global__ __launch_bounds__(256) void k_agg2(const int* __restrict__ row_ptr,
                                              const int* __restrict__ src_sorted,
                                              const float* __restrict__ e4,
                                              const float* __restrict__ als,
                                              const float* __restrict__ ald,
                                              const f16* __restrict__ xp,
                                              f16* __restrict__ aggcat) {
    constexpr int EPL = CIN / 64;  // halfs per lane
    int wid = threadIdx.x >> 6, lane = threadIdx.x & 63;
    int node = blockIdx.x * 4 + wid;
    int beg = row_ptr[node], end = row_ptr[node + 1];
    float4 ad4 = ((const float4*)ald)[node];
    const float4* e44 = (const float4*)e4;
    const float4* als4 = (const float4*)als;
    float s0 = 0.f, s1 = 0.f, s2 = 0.f, s3 = 0.f;
    float a0[EPL] = {}, a1[EPL] = {}, a2[EPL] = {}, a3[EPL] = {};
    const f16* xbase = xp + lane * EPL;
#pragma unroll 2
    for (int j = beg; j < end; ++j) {
        int src = src_sorted[j];
        float4 ev = e44[j];
        float4 av = als4[src];
        float e0 = __expf(lrelu(ev.x + av.x + ad4.x));
        float e1 = __expf(lrelu(ev.y + av.y + ad4.y));
        float e2 = __expf(lrelu(ev.z + av.z + ad4.z));
        float e3 = __expf(lrelu(ev.w + av.w + ad4.w));
        s0 += e0; s1 += e1; s2 += e2; s3 += e3;
        const f16* xr = xbase + (size_t)src * CIN;
        if (EPL == 2) {
            f16x2 v = *(const f16x2*)xr;
            float f0 = (float)v[0], f1 = (float)v[1];
            a0[0] += e0 * f0; a0[1] += e0 * f1;
            a1[0] += e1 * f0; a1[1] += e1 * f1;
            a2[0] += e2 * f0; a2[1] += e2 * f1;
            a3[0] += e3 * f0; a3[1] += e3 * f1;
        } else {
            f16x4 v = *(const f16x4*)xr;
#pragma unroll
            for (int i = 0; i < 4; ++i) {
                float f = (float)v[i];
                a0[i] += e0 * f; a1[i] += e1 * f; a2[i] += e2 * f; a3[i] += e3 * f;
            }
        }
    }
    float i0 = 1.f / (s0 + 1e-16f), i1 = 1.f / (s1 + 1e-16f);
    float i2 = 1.f / (s2 + 1e-16f), i3 = 1.f / (s3 + 1e-16f);
    f16* ob = aggcat + (size_t)node * 4 * CIN + lane * EPL;
    if (EPL == 2) {
        f16x2 o;
        o[0] = (f16)(a0[0] * i0); o[1] = (f16)(a0[1] * i0); *(f16x2*)(ob + 0 * CIN) = o;
        o[0] = (f16)(a1[0] * i1); o[1] = (f16)(a1[1] * i1); *(f16x2*)(ob + 1 * CIN) = o;
        o[0] = (f16)(a2[0] * i2); o[1] = (f16)(a2[1] * i2); *(f16x2*)(ob + 2 * CIN) = o;
        o[0] = (f16)(a3[0] * i3); o[1] = (f16)(a3[1] * i3); *(f16x2*)(ob + 3 * CIN) = o;
    } else {
        f16x4 o;
#pragma unroll
        for (int i = 0; i < 4; ++i) o[i] = (f16)(a0[i] * i0);
        *(f16x4*)(ob + 0 * CIN) = o;
#pragma unroll
        for (int i = 0; i < 4; ++i) o[i] = (f16)(a1[i] * i1);
        *(f16x4*)(ob + 1 * CIN) = o;
#pragma unroll
        for (int i = 0; i < 4; ++i) o[i] = (f16)(a2[i] * i2);
        *(f16x4*)(ob + 2 * CIN) = o;
#pragma unroll
        for (int i = 0; i < 4; ++i) o[i] = (f16)(a3[i] * i3);
        *(f16x4*)(ob + 3 * CIN) = o;
    }
}

// ===== MFMA GEMM + epilogue: hout = elu(0.25*A@Bt^T + b), fp16 out =====
// A[NN][K4] f16, Bt[C][K4] f16. 64x64 tile, 4 waves of 32x32.
template <int K4, int C>
__global__ __launch_bounds__(256) void k_gemm_ep(const f16* __restrict__ A,
                                                 const f16* __restrict__ Bt,
                                                 const float* __restrict__ bias,
                                                 f16* __restrict__ hout) {
    __shared__ f16 Als[64 * 40];
    __shared__ f16 Bls[64 * 40];
    int bm = blockIdx.x * 64, bn = blockIdx.y * 64;
    int tid = threadIdx.x;
    int wid = tid >> 6, lane = tid & 63;
    int wrow = (wid >> 1) * 32, wcol = (wid & 1) * 32;
    int fr = lane & 15, fk = (lane >> 4) * 8;
    f32x4 acc[2][2];
#pragma unroll
    for (int m = 0; m < 2; ++m)
#pragma unroll
        for (int n = 0; n < 2; ++n) acc[m][n] = (f32x4){0.f, 0.f, 0.f, 0.f};

    int srow = tid >> 2, spart = tid & 3;
    for (int k0 = 0; k0 < K4; k0 += 32) {
        int gr = bm + srow;
        u16x8 va = (u16x8)0;
        if (gr < NN) va = *(const u16x8*)(A + (size_t)gr * K4 + k0 + spart * 8);
        *(u16x8*)&Als[srow * 40 + spart * 8] = va;
        u16x8 vb = *(const u16x8*)(Bt + (size_t)(bn + srow) * K4 + k0 + spart * 8);
        *(u16x8*)&Bls[srow * 40 + spart * 8] = vb;
        __syncthreads();
        f16x8 af[2], bf[2];
        af[0] = *(const f16x8*)&Als[(wrow + fr) * 40 + fk];
        af[1] = *(const f16x8*)&Als[(wrow + 16 + fr) * 40 + fk];
        bf[0] = *(const f16x8*)&Bls[(wcol + fr) * 40 + fk];
        bf[1] = *(const f16x8*)&Bls[(wcol + 16 + fr) * 40 + fk];
#pragma unroll
        for (int m = 0; m < 2; ++m)
#pragma unroll
            for (int n = 0; n < 2; ++n)
                acc[m][n] = __builtin_amdgcn_mfma_f32_16x16x32_f16(af[m], bf[n], acc[m][n], 0, 0, 0);
        __syncthreads();
    }

    int cr = (lane >> 4) * 4, cc = lane & 15;
    float b0 = bias[bn + wcol + cc], b1 = bias[bn + wcol + 16 + cc];
#pragma unroll
    for (int m = 0; m < 2; ++m) {
#pragma unroll
        for (int r = 0; r < 4; ++r) {
            int row = bm + wrow + m * 16 + cr + r;
            if (row >= NN) continue;
            f16* cp = hout + (size_t)row * C + bn + wcol + cc;
            cp[0]  = (f16)elu1(0.25f * acc[m][0][r] + b0);
            cp[16] = (f16)elu1(0.25f * acc[m][1][r] + b1);
        }
    }
}

// ============================ pooling (batch sorted) ============================

__global__ void k_pool(const f16* __restrict__ h, const int* __restrict__ batch,
                       float* __restrict__ out) {
    int g = blockIdx.x;   // 64
    int c = threadIdx.x;  // 128
    int lo = 0, hi = NN;
    while (lo < hi) { int mid = (lo + hi) >> 1; if (batch[mid] < g) lo = mid + 1; else hi = mid; }
    int start = lo;
    lo = start; hi = NN;
    while (lo < hi) { int mid = (lo + hi) >> 1; if (batch[mid] < g + 1) lo = mid + 1; else hi = mid; }
    int stop = lo;
    float v = 0.f;
    for (int n = start; n < stop; ++n) v += (float)h[(size_t)n * 128 + c];
    out[g * 128 + c] = v / fmaxf((float)(stop - start), 1.f);
}

// ============================ host side ============================

struct Ws {
    f16 *x16, *hA, *hB, *aggcat, *Wt1, *Wt2, *Wt3;
    float *als, *ald, *esum, *e4all, *asd1, *asd2, *asd3, *Wf1, *Wf2, *Wf3;
    int *deg, *row_ptr, *cursor, *src_sorted, *eid_sorted, *pos;
};

static void carve(void* base, Ws& w) {
    char* p = (char*)base;
    size_t off = 0;
    auto take = [&](size_t bytes) {
        off = (off + 255) & ~(size_t)255;
        void* r = p + off;
        off += bytes;
        return r;
    };
    w.x16        = (f16*)take((size_t)NN * 128 * 2);
    w.hA         = (f16*)take((size_t)NN * 128 * 2);
    w.hB         = (f16*)take((size_t)NN * 256 * 2);
    w.aggcat     = (f16*)take((size_t)NN * 1024 * 2);
    w.Wt1        = (f16*)take((size_t)512 * 128 * 2);
    w.Wt2        = (f16*)take((size_t)512 * 256 * 2);
    w.Wt3        = (f16*)take((size_t)1024 * 128 * 2);
    w.als        = (float*)take((size_t)NN * 4 * 4);
    w.ald        = (float*)take((size_t)NN * 4 * 4);
    w.esum       = (float*)take((size_t)NN * EDIM * 4);
    w.e4all      = (float*)take((size_t)3 * NE2 * 4 * 4);
    w.asd1       = (float*)take(2 * 4 * 128 * 4);
    w.asd2       = (float*)take(2 * 4 * 128 * 4);
    w.asd3       = (float*)take(2 * 4 * 256 * 4);
    w.Wf1        = (float*)take(128 * 4);
    w.Wf2        = (float*)take(128 * 4);
    w.Wf3        = (float*)take(128 * 4);
    w.deg        = (int*)take((size_t)NN * 4);
    w.row_ptr    = (int*)take((size_t)(NN + 1) * 4);
    w.cursor     = (int*)take((size_t)NN * 4);
    w.src_sorted = (int*)take((size_t)NE2 * 4);
    w.eid_sorted = (int*)take((size_t)NE2 * 4);
    w.pos        = (int*)take((size_t)NE2 * 4);
}

extern "C" void kernel_launch(void* const* d_in, const int* in_sizes, int n_in,
                              void* d_out, int out_size, void* d_ws, size_t ws_size,
                              hipStream_t stream) {
    const float* x     = (const float*)d_in[0];
    const int*   ei    = (const int*)d_in[1];
    const float* eattr = (const float*)d_in[2];
    const int*   batch = (const int*)d_in[3];
    const float* W[3]  = {(const float*)d_in[4],  (const float*)d_in[10], (const float*)d_in[16]};
    const float* We[3] = {(const float*)d_in[5],  (const float*)d_in[11], (const float*)d_in[17]};
    const float* as_[3]= {(const float*)d_in[6],  (const float*)d_in[12], (const float*)d_in[18]};
    const float* ad_[3]= {(const float*)d_in[7],  (const float*)d_in[13], (const float*)d_in[19]};
    const float* ae_[3]= {(const float*)d_in[8],  (const float*)d_in[14], (const float*)d_in[20]};
    const float* b_[3] = {(const float*)d_in[9],  (const float*)d_in[15], (const float*)d_in[21]};
    float* out = (float*)d_out;

    Ws w;
    carve(d_ws, w);

    hipMemsetAsync(w.deg, 0, (size_t)NN * 4, stream);

    // ---- weight prep (independent of node data) ----
    k_wprep<128, 128><<<67, 256, 0, stream>>>(W[0], We[0], as_[0], ad_[0], ae_[0],
                                              w.Wt1, w.asd1, w.Wf1);
    k_wprep<128, 256><<<131, 256, 0, stream>>>(W[1], We[1], as_[1], ad_[1], ae_[1],
                                               w.Wt2, w.asd2, w.Wf2);
    k_wprep<256, 128><<<133, 256, 0, stream>>>(W[2], We[2], as_[2], ad_[2], ae_[2],
                                               w.Wt3, w.asd3, w.Wf3);

    // ---- graph preprocessing ----
    k_deg<<<(NE + 255) / 256, 256, 0, stream>>>(ei, w.deg);
    k_scan2<<<1, 1024, 0, stream>>>(w.deg, w.row_ptr, w.cursor);
    k_fill<<<(NE2 + 255) / 256, 256, 0, stream>>>(ei, w.cursor, w.src_sorted,
                                                  w.eid_sorted, w.pos);
    k_esum<<<NN / 4, 256, 0, stream>>>(w.row_ptr, w.eid_sorted, eattr, w.esum);
    k_xcast<<<(NN * 128 / 4 + 255) / 256, 256, 0, stream>>>(x, w.x16);
    k_e4<<<(NE2 + 255) / 256, 256, 0, stream>>>(eattr, w.esum, w.deg,
                                                w.Wf1, w.Wf2, w.Wf3, w.pos, w.e4all);

    const float* e4_1 = w.e4all;
    const float* e4_2 = w.e4all + (size_t)NE2 * 4;
    const float* e4_3 = w.e4all + (size_t)2 * NE2 * 4;

    // ---- layer 1 (CIN=128, C=128) ----
    k_alnode2<128><<<NN / 4, 256, 0, stream>>>(w.x16, w.asd1, w.als, w.ald);
    k_agg2<128><<<NN / 4, 256, 0, stream>>>(w.row_ptr, w.src_sorted, e4_1, w.als, w.ald,
                                            w.x16, w.aggcat);
    k_gemm_ep<512, 128><<<dim3(157, 2), 256, 0, stream>>>(w.aggcat, w.Wt1, b_[0], w.hA);

    // ---- layer 2 (CIN=128, C=256) ----
    k_alnode2<128><<<NN / 4, 256, 0, stream>>>(w.hA, w.asd2, w.als, w.ald);
    k_agg2<128><<<NN / 4, 256, 0, stream>>>(w.row_ptr, w.src_sorted, e4_2, w.als, w.ald,
                                            w.hA, w.aggcat);
    k_gemm_ep<512, 256><<<dim3(157, 4), 256, 0, stream>>>(w.aggcat, w.Wt2, b_[1], w.hB);

    // ---- layer 3 (CIN=256, C=128) ----
    k_alnode2<256><<<NN / 4, 256, 0, stream>>>(w.hB, w.asd3, w.als, w.ald);
    k_agg2<256><<<NN / 4, 256, 0, stream>>>(w.row_ptr, w.src_sorted, e4_3, w.als, w.ald,
                                            w.hB, w.aggcat);
    k_gemm_ep<1024, 128><<<dim3(157, 2), 256, 0, stream>>>(w.aggcat, w.Wt3, b_[2], w.hA);

    // ---- global mean pool ----
    k_pool<<<NG, 128, 0, stream>>>(w.hA, batch, out);
}

// Round 5
// 348.668 us; speedup vs baseline: 2.9140x; 1.1361x over previous
//
#include <hip/hip_runtime.h>

#define NN 10000
#define NE 160000
#define NE2 (NE + NN)
#define NG 64
#define EDIM 32

typedef _Float16 f16;
typedef __attribute__((ext_vector_type(2))) _Float16 f16x2;
typedef __attribute__((ext_vector_type(4))) _Float16 f16x4;
typedef __attribute__((ext_vector_type(8))) _Float16 f16x8;
typedef __attribute__((ext_vector_type(4))) float f32x4;
typedef __attribute__((ext_vector_type(8))) unsigned short u16x8;

__device__ __forceinline__ float lrelu(float x) { return fmaxf(x, 0.2f * x); }
__device__ __forceinline__ float elu1(float x) { return x > 0.f ? x : __expf(x) - 1.f; }

// ============== merged prep: deg atomics (blocks 0..624) + x fp16 cast ==============

__global__ __launch_bounds__(256) void k_prep(const int* __restrict__ ei,
                                              int* __restrict__ deg,
                                              const float* __restrict__ x,
                                              f16* __restrict__ x16) {
    int b = blockIdx.x, tid = threadIdx.x;
    if (b < 625) {
        int e = b * 256 + tid;
        atomicAdd(&deg[ei[NE + e]], 1);
    } else {
        int i = (b - 625) * 256 + tid;  // per 4 elems, 1250 blocks exactly
        float4 v = ((const float4*)x)[i];
        f16x4 o;
        o[0] = (f16)v.x; o[1] = (f16)v.y; o[2] = (f16)v.z; o[3] = (f16)v.w;
        *(f16x4*)(x16 + i * 4) = o;
    }
}

// ============== scan (row_ptr/cursor) + group inv-counts ==============

__global__ __launch_bounds__(1024) void k_scan2(const int* __restrict__ deg,
                                                int* __restrict__ row_ptr,
                                                int* __restrict__ cursor,
                                                const int* __restrict__ batch,
                                                float* __restrict__ invc) {
    int tid = threadIdx.x;
    int vals[10];
    int run = 0;
#pragma unroll
    for (int i = 0; i < 10; ++i) {
        int n = tid * 10 + i;
        int v = (n < NN) ? (deg[n] + 1) : 0;
        run += v;
        vals[i] = run;
    }
    int total = run;
    int lane = tid & 63, wid = tid >> 6;
    int sc = total;
#pragma unroll
    for (int off = 1; off < 64; off <<= 1) {
        int t = __shfl_up(sc, off);
        if (lane >= off) sc += t;
    }
    __shared__ int wsum[16];
    if (lane == 63) wsum[wid] = sc;
    __syncthreads();
    if (tid == 0) {
        int a = 0;
#pragma unroll
        for (int w = 0; w < 16; ++w) { int t = wsum[w]; wsum[w] = a; a += t; }
    }
    __syncthreads();
    int excl = sc - total + wsum[wid];
#pragma unroll
    for (int i = 0; i < 10; ++i) {
        int n = tid * 10 + i;
        if (n < NN) {
            int prev = i ? vals[i - 1] : 0;
            row_ptr[n + 1] = excl + vals[i];
            cursor[n] = excl + prev;
        }
    }
    if (tid == 0) row_ptr[0] = 0;
    // group inv-counts (batch sorted): threads 0..63
    if (tid < NG) {
        int g = tid;
        int lo = 0, hi = NN;
        while (lo < hi) { int mid = (lo + hi) >> 1; if (batch[mid] < g) lo = mid + 1; else hi = mid; }
        int start = lo;
        lo = start; hi = NN;
        while (lo < hi) { int mid = (lo + hi) >> 1; if (batch[mid] < g + 1) lo = mid + 1; else hi = mid; }
        invc[g] = 1.f / fmaxf((float)(lo - start), 1.f);
    }
}

__global__ void k_fill(const int* __restrict__ ei, int* __restrict__ cursor,
                       int* __restrict__ src_sorted, int* __restrict__ eid_sorted,
                       int* __restrict__ pos) {
    int e = blockIdx.x * blockDim.x + threadIdx.x;
    if (e >= NE2) return;
    int s, d;
    if (e < NE) { s = ei[e]; d = ei[NE + e]; }
    else        { s = d = e - NE; }
    int p = atomicAdd(&cursor[d], 1);
    src_sorted[p] = s;
    eid_sorted[p] = e;
    pos[e] = p;
}

__global__ __launch_bounds__(256) void k_esum(const int* __restrict__ row_ptr,
                                              const int* __restrict__ eid_sorted,
                                              const float* __restrict__ eattr,
                                              float* __restrict__ esum) {
    int wid = threadIdx.x >> 6, lane = threadIdx.x & 63;
    int node = blockIdx.x * 4 + wid;
    int d = lane & 31, sel = lane >> 5;
    int beg = row_ptr[node], end = row_ptr[node + 1];
    float v = 0.f;
    for (int j = beg + sel; j < end; j += 2) {
        int eid = eid_sorted[j];
        if (eid < NE) v += eattr[(size_t)eid * EDIM + d];
    }
    v += __shfl_xor(v, 32);
    if (sel == 0) esum[node * EDIM + d] = v;
}

// ========== weight prep (all 3 layers in one launch via block ranges) ==========

template <int CIN, int C>
__device__ __forceinline__ void wprep_body(int b, int tid,
                                           const float* __restrict__ W,
                                           const float* __restrict__ We,
                                           const float* __restrict__ as_,
                                           const float* __restrict__ ad_,
                                           const float* __restrict__ ae_,
                                           f16* __restrict__ Bt,
                                           float* __restrict__ asd,
                                           float* __restrict__ Wf,
                                           float (*t)[33]) {
    constexpr int K4 = 4 * CIN;
    constexpr int KT = CIN / 32, CT = C / 32;
    constexpr int TB = 4 * KT * CT;
    constexpr int FB = CIN / 64;
    if (b < TB) {
        int h = b / (KT * CT);
        int rem = b % (KT * CT);
        int k0 = (rem / CT) * 32, c0 = (rem % CT) * 32;
        int i = tid >> 5, j = tid & 31;
#pragma unroll
        for (int it = 0; it < 4; ++it)
            t[i + it * 8][j] = W[(size_t)(k0 + i + it * 8) * (4 * C) + h * C + c0 + j];
        __syncthreads();
#pragma unroll
        for (int it = 0; it < 4; ++it) {
            int jj = (tid >> 5) + it * 8, ii = tid & 31;
            Bt[(size_t)(c0 + jj) * K4 + h * CIN + k0 + ii] = (f16)t[ii][jj];
        }
    } else if (b < TB + FB) {
        int k = (b - TB) * 64 + (tid >> 2), h = tid & 3;
        const float4* wr = (const float4*)(W + (size_t)k * (4 * C) + h * C);
        const float4* a4 = (const float4*)(as_ + h * C);
        const float4* d4 = (const float4*)(ad_ + h * C);
        float s = 0.f, d = 0.f;
        for (int c = 0; c < C / 4; ++c) {
            float4 w = wr[c], av = a4[c], dv = d4[c];
            s += w.x * av.x + w.y * av.y + w.z * av.z + w.w * av.w;
            d += w.x * dv.x + w.y * dv.y + w.z * dv.z + w.w * dv.w;
        }
        asd[h * CIN + k] = s;
        asd[4 * CIN + h * CIN + k] = d;
    } else if (tid < 128) {
        int dd = tid >> 2, h = tid & 3;
        const float4* wr = (const float4*)(We + (size_t)dd * (4 * C) + h * C);
        const float4* a4 = (const float4*)(ae_ + h * C);
        float s = 0.f;
        for (int c = 0; c < C / 4; ++c) {
            float4 w = wr[c], av = a4[c];
            s += w.x * av.x + w.y * av.y + w.z * av.z + w.w * av.w;
        }
        Wf[dd * 4 + h] = s;
    }
}

__global__ __launch_bounds__(256) void k_wprep_all(
    const float* W1, const float* We1, const float* as1, const float* ad1, const float* ae1,
    f16* Bt1, float* asd1, float* Wf1,
    const float* W2, const float* We2, const float* as2, const float* ad2, const float* ae2,
    f16* Bt2, float* asd2, float* Wf2,
    const float* W3, const float* We3, const float* as3, const float* ad3, const float* ae3,
    f16* Bt3, float* asd3, float* Wf3) {
    __shared__ float t[32][33];
    int b = blockIdx.x, tid = threadIdx.x;
    if (b < 67)       wprep_body<128, 128>(b,       tid, W1, We1, as1, ad1, ae1, Bt1, asd1, Wf1, t);
    else if (b < 198) wprep_body<128, 256>(b - 67,  tid, W2, We2, as2, ad2, ae2, Bt2, asd2, Wf2, t);
    else              wprep_body<256, 128>(b - 198, tid, W3, We3, as3, ad3, ae3, Bt3, asd3, Wf3, t);
}

// per-edge attention contributions for all 3 layers, written CSR-ordered
__global__ __launch_bounds__(256) void k_e4(const float* __restrict__ eattr,
                                            const float* __restrict__ esum,
                                            const int* __restrict__ deg,
                                            const float* __restrict__ Wf1,
                                            const float* __restrict__ Wf2,
                                            const float* __restrict__ Wf3,
                                            const int* __restrict__ pos,
                                            float* __restrict__ e4all) {
    __shared__ float wf[3][128];
    int tid = threadIdx.x;
    if (tid < 128) { wf[0][tid] = Wf1[tid]; wf[1][tid] = Wf2[tid]; wf[2][tid] = Wf3[tid]; }
    __syncthreads();
    int e = blockIdx.x * 256 + tid;
    if (e >= NE2) return;
    const float4* er;
    float scale = 1.f;
    if (e < NE) {
        er = (const float4*)(eattr + (size_t)e * EDIM);
    } else {
        int n = e - NE;
        er = (const float4*)(esum + (size_t)n * EDIM);
        scale = 1.f / fmaxf((float)deg[n], 1.f);
    }
    float4 v[8];
#pragma unroll
    for (int i = 0; i < 8; ++i) v[i] = er[i];
    int p = pos[e];
#pragma unroll
    for (int l = 0; l < 3; ++l) {
        float a0 = 0.f, a1 = 0.f, a2 = 0.f, a3 = 0.f;
#pragma unroll
        for (int d4 = 0; d4 < 8; ++d4) {
            const float* w = &wf[l][d4 * 16];
            a0 += v[d4].x * w[0] + v[d4].y * w[4] + v[d4].z * w[8]  + v[d4].w * w[12];
            a1 += v[d4].x * w[1] + v[d4].y * w[5] + v[d4].z * w[9]  + v[d4].w * w[13];
            a2 += v[d4].x * w[2] + v[d4].y * w[6] + v[d4].z * w[10] + v[d4].w * w[14];
            a3 += v[d4].x * w[3] + v[d4].y * w[7] + v[d4].z * w[11] + v[d4].w * w[15];
        }
        ((float4*)e4all)[(size_t)l * NE2 + p] =
            make_float4(a0 * scale, a1 * scale, a2 * scale, a3 * scale);
    }
}

// als[n,h] = x'[n]·âs[h], ald likewise. Wave per node; lane = (h, 16-chunk).
template <int CIN>
__global__ __launch_bounds__(256) void k_alnode2(const f16* __restrict__ xp,
                                                 const float* __restrict__ asd,
                                                 float* __restrict__ als,
                                                 float* __restrict__ ald) {
    __shared__ float sA[4 * CIN], sD[4 * CIN];
    for (int i = threadIdx.x; i < 4 * CIN; i += 256) { sA[i] = asd[i]; sD[i] = asd[4 * CIN + i]; }
    __syncthreads();
    int wid = threadIdx.x >> 6, lane = threadIdx.x & 63;
    int node = blockIdx.x * 4 + wid;
    int h = lane >> 4, c16 = lane & 15;
    constexpr int KC = CIN / 16;
    const f16* xr = xp + (size_t)node * CIN + c16 * KC;
    float s = 0.f, d = 0.f;
#pragma unroll
    for (int p = 0; p < KC / 8; ++p) {
        f16x8 v = *(const f16x8*)(xr + p * 8);
        const float* wa = &sA[h * CIN + c16 * KC + p * 8];
        const float* wd = &sD[h * CIN + c16 * KC + p * 8];
#pragma unroll
        for (int i = 0; i < 8; ++i) {
            float f = (float)v[i];
            s += f * wa[i];
            d += f * wd[i];
        }
    }
#pragma unroll
    for (int off = 1; off < 16; off <<= 1) { s += __shfl_xor(s, off); d += __shfl_xor(d, off); }
    if (c16 == 0) { als[node * 4 + h] = s; ald[node * 4 + h] = d; }
}

// fused logits + softmax (no max pass) + INPUT-feature aggregation.
template <int CIN>
__global__ __launch_bounds__(256) void k_agg2(const int* __restrict__ row_ptr,
                                              const int* __restrict__ src_sorted,
                                              const float* __restrict__ e4,
                                              const float* __restrict__ als,
                                              const float* __restrict__ ald,
                                              const f16* __restrict__ xp,
                                              f16* __restrict__ aggcat) {
    constexpr int EPL = CIN / 64;  // halfs per lane
    int wid = threadIdx.x >> 6, lane = threadIdx.x & 63;
    int node = blockIdx.x * 4 + wid;
    int beg = row_ptr[node], end = row_ptr[node + 1];
    float4 ad4 = ((const float4*)ald)[node];
    const float4* e44 = (const float4*)e4;
    const float4* als4 = (const float4*)als;
    float s0 = 0.f, s1 = 0.f, s2 = 0.f, s3 = 0.f;
    float a0[EPL] = {}, a1[EPL] = {}, a2[EPL] = {}, a3[EPL] = {};
    const f16* xbase = xp + lane * EPL;
#pragma unroll 4
    for (int j = beg; j < end; ++j) {
        int src = src_sorted[j];
        float4 ev = e44[j];
        float4 av = als4[src];
        float e0 = __expf(lrelu(ev.x + av.x + ad4.x));
        float e1 = __expf(lrelu(ev.y + av.y + ad4.y));
        float e2 = __expf(lrelu(ev.z + av.z + ad4.z));
        float e3 = __expf(lrelu(ev.w + av.w + ad4.w));
        s0 += e0; s1 += e1; s2 += e2; s3 += e3;
        const f16* xr = xbase + (size_t)src * CIN;
        if (EPL == 2) {
            f16x2 v = *(const f16x2*)xr;
            float f0 = (float)v[0], f1 = (float)v[1];
            a0[0] += e0 * f0; a0[1] += e0 * f1;
            a1[0] += e1 * f0; a1[1] += e1 * f1;
            a2[0] += e2 * f0; a2[1] += e2 * f1;
            a3[0] += e3 * f0; a3[1] += e3 * f1;
        } else {
            f16x4 v = *(const f16x4*)xr;
#pragma unroll
            for (int i = 0; i < 4; ++i) {
                float f = (float)v[i];
                a0[i] += e0 * f; a1[i] += e1 * f; a2[i] += e2 * f; a3[i] += e3 * f;
            }
        }
    }
    float i0 = 1.f / (s0 + 1e-16f), i1 = 1.f / (s1 + 1e-16f);
    float i2 = 1.f / (s2 + 1e-16f), i3 = 1.f / (s3 + 1e-16f);
    f16* ob = aggcat + (size_t)node * 4 * CIN + lane * EPL;
    if (EPL == 2) {
        f16x2 o;
        o[0] = (f16)(a0[0] * i0); o[1] = (f16)(a0[1] * i0); *(f16x2*)(ob + 0 * CIN) = o;
        o[0] = (f16)(a1[0] * i1); o[1] = (f16)(a1[1] * i1); *(f16x2*)(ob + 1 * CIN) = o;
        o[0] = (f16)(a2[0] * i2); o[1] = (f16)(a2[1] * i2); *(f16x2*)(ob + 2 * CIN) = o;
        o[0] = (f16)(a3[0] * i3); o[1] = (f16)(a3[1] * i3); *(f16x2*)(ob + 3 * CIN) = o;
    } else {
        f16x4 o;
#pragma unroll
        for (int i = 0; i < 4; ++i) o[i] = (f16)(a0[i] * i0);
        *(f16x4*)(ob + 0 * CIN) = o;
#pragma unroll
        for (int i = 0; i < 4; ++i) o[i] = (f16)(a1[i] * i1);
        *(f16x4*)(ob + 1 * CIN) = o;
#pragma unroll
        for (int i = 0; i < 4; ++i) o[i] = (f16)(a2[i] * i2);
        *(f16x4*)(ob + 2 * CIN) = o;
#pragma unroll
        for (int i = 0; i < 4; ++i) o[i] = (f16)(a3[i] * i3);
        *(f16x4*)(ob + 3 * CIN) = o;
    }
}

// ===== MFMA GEMM + epilogue: hout = elu(0.25*A@Bt^T + b), fp16 out =====
template <int K4, int C>
__global__ __launch_bounds__(256) void k_gemm_ep(const f16* __restrict__ A,
                                                 const f16* __restrict__ Bt,
                                                 const float* __restrict__ bias,
                                                 f16* __restrict__ hout) {
    __shared__ f16 Als[64 * 40];
    __shared__ f16 Bls[64 * 40];
    int bm = blockIdx.x * 64, bn = blockIdx.y * 64;
    int tid = threadIdx.x;
    int wid = tid >> 6, lane = tid & 63;
    int wrow = (wid >> 1) * 32, wcol = (wid & 1) * 32;
    int fr = lane & 15, fk = (lane >> 4) * 8;
    f32x4 acc[2][2];
#pragma unroll
    for (int m = 0; m < 2; ++m)
#pragma unroll
        for (int n = 0; n < 2; ++n) acc[m][n] = (f32x4){0.f, 0.f, 0.f, 0.f};

    int srow = tid >> 2, spart = tid & 3;
    for (int k0 = 0; k0 < K4; k0 += 32) {
        int gr = bm + srow;
        u16x8 va = (u16x8)0;
        if (gr < NN) va = *(const u16x8*)(A + (size_t)gr * K4 + k0 + spart * 8);
        *(u16x8*)&Als[srow * 40 + spart * 8] = va;
        u16x8 vb = *(const u16x8*)(Bt + (size_t)(bn + srow) * K4 + k0 + spart * 8);
        *(u16x8*)&Bls[srow * 40 + spart * 8] = vb;
        __syncthreads();
        f16x8 af[2], bf[2];
        af[0] = *(const f16x8*)&Als[(wrow + fr) * 40 + fk];
        af[1] = *(const f16x8*)&Als[(wrow + 16 + fr) * 40 + fk];
        bf[0] = *(const f16x8*)&Bls[(wcol + fr) * 40 + fk];
        bf[1] = *(const f16x8*)&Bls[(wcol + 16 + fr) * 40 + fk];
#pragma unroll
        for (int m = 0; m < 2; ++m)
#pragma unroll
            for (int n = 0; n < 2; ++n)
                acc[m][n] = __builtin_amdgcn_mfma_f32_16x16x32_f16(af[m], bf[n], acc[m][n], 0, 0, 0);
        __syncthreads();
    }

    int cr = (lane >> 4) * 4, cc = lane & 15;
    float b0 = bias[bn + wcol + cc], b1 = bias[bn + wcol + 16 + cc];
#pragma unroll
    for (int m = 0; m < 2; ++m) {
#pragma unroll
        for (int r = 0; r < 4; ++r) {
            int row = bm + wrow + m * 16 + cr + r;
            if (row >= NN) continue;
            f16* cp = hout + (size_t)row * C + bn + wcol + cc;
            cp[0]  = (f16)elu1(0.25f * acc[m][0][r] + b0);
            cp[16] = (f16)elu1(0.25f * acc[m][1][r] + b1);
        }
    }
}

// ===== layer-3 GEMM with fused mean-pool epilogue (atomicAdd into out) =====
template <int K4, int C>
__global__ __launch_bounds__(256) void k_gemm_pool(const f16* __restrict__ A,
                                                   const f16* __restrict__ Bt,
                                                   const float* __restrict__ bias,
                                                   const int* __restrict__ batch,
                                                   const float* __restrict__ invc,
                                                   float* __restrict__ out) {
    __shared__ f16 Als[64 * 40];
    __shared__ f16 Bls[64 * 40];
    int bm = blockIdx.x * 64, bn = blockIdx.y * 64;
    int tid = threadIdx.x;
    int wid = tid >> 6, lane = tid & 63;
    int wrow = (wid >> 1) * 32, wcol = (wid & 1) * 32;
    int fr = lane & 15, fk = (lane >> 4) * 8;
    f32x4 acc[2][2];
#pragma unroll
    for (int m = 0; m < 2; ++m)
#pragma unroll
        for (int n = 0; n < 2; ++n) acc[m][n] = (f32x4){0.f, 0.f, 0.f, 0.f};

    int srow = tid >> 2, spart = tid & 3;
    for (int k0 = 0; k0 < K4; k0 += 32) {
        int gr = bm + srow;
        u16x8 va = (u16x8)0;
        if (gr < NN) va = *(const u16x8*)(A + (size_t)gr * K4 + k0 + spart * 8);
        *(u16x8*)&Als[srow * 40 + spart * 8] = va;
        u16x8 vb = *(const u16x8*)(Bt + (size_t)(bn + srow) * K4 + k0 + spart * 8);
        *(u16x8*)&Bls[srow * 40 + spart * 8] = vb;
        __syncthreads();
        f16x8 af[2], bf[2];
        af[0] = *(const f16x8*)&Als[(wrow + fr) * 40 + fk];
        af[1] = *(const f16x8*)&Als[(wrow + 16 + fr) * 40 + fk];
        bf[0] = *(const f16x8*)&Bls[(wcol + fr) * 40 + fk];
        bf[1] = *(const f16x8*)&Bls[(wcol + 16 + fr) * 40 + fk];
#pragma unroll
        for (int m = 0; m < 2; ++m)
#pragma unroll
            for (int n = 0; n < 2; ++n)
                acc[m][n] = __builtin_amdgcn_mfma_f32_16x16x32_f16(af[m], bf[n], acc[m][n], 0, 0, 0);
        __syncthreads();
    }

    int cr = (lane >> 4) * 4, cc = lane & 15;
    float b0 = bias[bn + wcol + cc], b1 = bias[bn + wcol + 16 + cc];
#pragma unroll
    for (int m = 0; m < 2; ++m) {
#pragma unroll
        for (int r = 0; r < 4; ++r) {
            int row = bm + wrow + m * 16 + cr + r;
            if (row >= NN) continue;
            int g = batch[row];
            float ic = invc[g];
            float* op = out + (size_t)g * C + bn + wcol + cc;
            atomicAdd(op,      elu1(0.25f * acc[m][0][r] + b0) * ic);
            atomicAdd(op + 16, elu1(0.25f * acc[m][1][r] + b1) * ic);
        }
    }
}

// ============================ host side ============================

struct Ws {
    f16 *x16, *hA, *hB, *aggcat, *Wt1, *Wt2, *Wt3;
    float *als, *ald, *esum, *e4all, *asd1, *asd2, *asd3, *Wf1, *Wf2, *Wf3, *invc;
    int *deg, *row_ptr, *cursor, *src_sorted, *eid_sorted, *pos;
};

static void carve(void* base, Ws& w) {
    char* p = (char*)base;
    size_t off = 0;
    auto take = [&](size_t bytes) {
        off = (off + 255) & ~(size_t)255;
        void* r = p + off;
        off += bytes;
        return r;
    };
    w.x16        = (f16*)take((size_t)NN * 128 * 2);
    w.hA         = (f16*)take((size_t)NN * 128 * 2);
    w.hB         = (f16*)take((size_t)NN * 256 * 2);
    w.aggcat     = (f16*)take((size_t)NN * 1024 * 2);
    w.Wt1        = (f16*)take((size_t)512 * 128 * 2);
    w.Wt2        = (f16*)take((size_t)512 * 256 * 2);
    w.Wt3        = (f16*)take((size_t)1024 * 128 * 2);
    w.als        = (float*)take((size_t)NN * 4 * 4);
    w.ald        = (float*)take((size_t)NN * 4 * 4);
    w.esum       = (float*)take((size_t)NN * EDIM * 4);
    w.e4all      = (float*)take((size_t)3 * NE2 * 4 * 4);
    w.asd1       = (float*)take(2 * 4 * 128 * 4);
    w.asd2       = (float*)take(2 * 4 * 128 * 4);
    w.asd3       = (float*)take(2 * 4 * 256 * 4);
    w.Wf1        = (float*)take(128 * 4);
    w.Wf2        = (float*)take(128 * 4);
    w.Wf3        = (float*)take(128 * 4);
    w.invc       = (float*)take(NG * 4);
    w.deg        = (int*)take((size_t)NN * 4);
    w.row_ptr    = (int*)take((size_t)(NN + 1) * 4);
    w.cursor     = (int*)take((size_t)NN * 4);
    w.src_sorted = (int*)take((size_t)NE2 * 4);
    w.eid_sorted = (int*)take((size_t)NE2 * 4);
    w.pos        = (int*)take((size_t)NE2 * 4);
}

extern "C" void kernel_launch(void* const* d_in, const int* in_sizes, int n_in,
                              void* d_out, int out_size, void* d_ws, size_t ws_size,
                              hipStream_t stream) {
    const float* x     = (const float*)d_in[0];
    const int*   ei    = (const int*)d_in[1];
    const float* eattr = (const float*)d_in[2];
    const int*   batch = (const int*)d_in[3];
    const float* W[3]  = {(const float*)d_in[4],  (const float*)d_in[10], (const float*)d_in[16]};
    const float* We[3] = {(const float*)d_in[5],  (const float*)d_in[11], (const float*)d_in[17]};
    const float* as_[3]= {(const float*)d_in[6],  (const float*)d_in[12], (const float*)d_in[18]};
    const float* ad_[3]= {(const float*)d_in[7],  (const float*)d_in[13], (const float*)d_in[19]};
    const float* ae_[3]= {(const float*)d_in[8],  (const float*)d_in[14], (const float*)d_in[20]};
    const float* b_[3] = {(const float*)d_in[9],  (const float*)d_in[15], (const float*)d_in[21]};
    float* out = (float*)d_out;

    Ws w;
    carve(d_ws, w);

    hipMemsetAsync(w.deg, 0, (size_t)NN * 4, stream);
    hipMemsetAsync(out, 0, (size_t)NG * 128 * 4, stream);

    // ---- weight prep (one launch, all 3 layers) ----
    k_wprep_all<<<331, 256, 0, stream>>>(
        W[0], We[0], as_[0], ad_[0], ae_[0], w.Wt1, w.asd1, w.Wf1,
        W[1], We[1], as_[1], ad_[1], ae_[1], w.Wt2, w.asd2, w.Wf2,
        W[2], We[2], as_[2], ad_[2], ae_[2], w.Wt3, w.asd3, w.Wf3);

    // ---- graph preprocessing ----
    k_prep<<<1875, 256, 0, stream>>>(ei, w.deg, x, w.x16);
    k_scan2<<<1, 1024, 0, stream>>>(w.deg, w.row_ptr, w.cursor, batch, w.invc);
    k_fill<<<(NE2 + 255) / 256, 256, 0, stream>>>(ei, w.cursor, w.src_sorted,
                                                  w.eid_sorted, w.pos);
    k_esum<<<NN / 4, 256, 0, stream>>>(w.row_ptr, w.eid_sorted, eattr, w.esum);
    k_e4<<<(NE2 + 255) / 256, 256, 0, stream>>>(eattr, w.esum, w.deg,
                                                w.Wf1, w.Wf2, w.Wf3, w.pos, w.e4all);

    const float* e4_1 = w.e4all;
    const float* e4_2 = w.e4all + (size_t)NE2 * 4;
    const float* e4_3 = w.e4all + (size_t)2 * NE2 * 4;

    // ---- layer 1 (CIN=128, C=128) ----
    k_alnode2<128><<<NN / 4, 256, 0, stream>>>(w.x16, w.asd1, w.als, w.ald);
    k_agg2<128><<<NN / 4, 256, 0, stream>>>(w.row_ptr, w.src_sorted, e4_1, w.als, w.ald,
                                            w.x16, w.aggcat);
    k_gemm_ep<512, 128><<<dim3(157, 2), 256, 0, stream>>>(w.aggcat, w.Wt1, b_[0], w.hA);

    // ---- layer 2 (CIN=128, C=256) ----
    k_alnode2<128><<<NN / 4, 256, 0, stream>>>(w.hA, w.asd2, w.als, w.ald);
    k_agg2<128><<<NN / 4, 256, 0, stream>>>(w.row_ptr, w.src_sorted, e4_2, w.als, w.ald,
                                            w.hA, w.aggcat);
    k_gemm_ep<512, 256><<<dim3(157, 4), 256, 0, stream>>>(w.aggcat, w.Wt2, b_[1], w.hB);

    // ---- layer 3 (CIN=256, C=128) with fused mean-pool ----
    k_alnode2<256><<<NN / 4, 256, 0, stream>>>(w.hB, w.asd3, w.als, w.ald);
    k_agg2<256><<<NN / 4, 256, 0, stream>>>(w.row_ptr, w.src_sorted, e4_3, w.als, w.ald,
                                            w.hB, w.aggcat);
    k_gemm_pool<1024, 128><<<dim3(157, 2), 256, 0, stream>>>(w.aggcat, w.Wt3, b_[2],
                                                             batch, w.invc, out);
}